// Round 5
// baseline (718.793 us; speedup 1.0000x reference)
//
#include <hip/hip_runtime.h>
#include <hip/hip_bf16.h>

#define S_LEN 4096
#define HDIM  2048
#define NHQ   8
#define NKVH  2
#define DHEAD 256
#define WIN   512

typedef __hip_bfloat16 bf16_t;
using fragAB = __attribute__((ext_vector_type(8))) short;  // 8 bf16
using fragC  = __attribute__((ext_vector_type(4))) float;  // 4 fp32

typedef unsigned int u32;
typedef const __attribute__((address_space(1))) u32* gas_ptr;
typedef __attribute__((address_space(3))) u32* las_ptr;

__device__ __forceinline__ void async_copy16(const void* g, void* l) {
  __builtin_amdgcn_global_load_lds((gas_ptr)g, (las_ptr)l, 16, 0, 0);
}

#define NEG_BIG (-3.0e38f)

__device__ __forceinline__ void split2(float x, bf16_t& hi, bf16_t& lo) {
  bf16_t h = __float2bfloat16(x);
  hi = h;
  lo = __float2bfloat16(x - (float)h);
}

// ---------------------------------------------------------------------------
// Elementwise split fp32 -> bf16 hi + bf16 lo  (n multiple of 1024)
// ---------------------------------------------------------------------------
__global__ __launch_bounds__(256) void split_f32(
    const float* __restrict__ in, bf16_t* __restrict__ hi,
    bf16_t* __restrict__ lo, int n) {
  int i = (blockIdx.x * 256 + threadIdx.x) * 4;
  if (i >= n) return;
  float4 v = *(const float4*)(in + i);
  split2(v.x, hi[i + 0], lo[i + 0]);
  split2(v.y, hi[i + 1], lo[i + 1]);
  split2(v.z, hi[i + 2], lo[i + 2]);
  split2(v.w, hi[i + 3], lo[i + 3]);
}

// ---------------------------------------------------------------------------
// Transpose+convert fp32 [R][C] -> bf16 [C][R]
// ---------------------------------------------------------------------------
__global__ __launch_bounds__(256) void transpose_cvt(
    const float* __restrict__ in, bf16_t* __restrict__ out, int R, int C) {
  __shared__ bf16_t tile[32][33];
  int c0 = blockIdx.x * 32, r0 = blockIdx.y * 32;
  int tx = threadIdx.x & 31, ty = threadIdx.x >> 5;
#pragma unroll
  for (int i = 0; i < 4; ++i)
    tile[ty + i * 8][tx] = __float2bfloat16(in[(size_t)(r0 + ty + i * 8) * C + c0 + tx]);
  __syncthreads();
#pragma unroll
  for (int i = 0; i < 4; ++i)
    out[(size_t)(c0 + ty + i * 8) * R + r0 + tx] = tile[tx][ty + i * 8];
}

// ---------------------------------------------------------------------------
// Transpose+split fp32 [R][C] -> bf16 hi [C][R], bf16 lo [C][R]
// ---------------------------------------------------------------------------
__global__ __launch_bounds__(256) void transpose_split(
    const float* __restrict__ in, bf16_t* __restrict__ hiT,
    bf16_t* __restrict__ loT, int R, int C) {
  __shared__ bf16_t th[32][33];
  __shared__ bf16_t tl[32][33];
  int c0 = blockIdx.x * 32, r0 = blockIdx.y * 32;
  int tx = threadIdx.x & 31, ty = threadIdx.x >> 5;
#pragma unroll
  for (int i = 0; i < 4; ++i) {
    float x = in[(size_t)(r0 + ty + i * 8) * C + c0 + tx];
    bf16_t h, l; split2(x, h, l);
    th[ty + i * 8][tx] = h;
    tl[ty + i * 8][tx] = l;
  }
  __syncthreads();
#pragma unroll
  for (int i = 0; i < 4; ++i) {
    hiT[(size_t)(c0 + ty + i * 8) * R + r0 + tx] = th[tx][ty + i * 8];
    loT[(size_t)(c0 + ty + i * 8) * R + r0 + tx] = tl[tx][ty + i * 8];
  }
}

// ---------------------------------------------------------------------------
// Plain GEMM: C[M][N] = A[M][K]*Bt[N][K]^T; bf16 in, fp32 accum, OutT out.
// ---------------------------------------------------------------------------
template <typename OutT>
__global__ __launch_bounds__(256) void gemm_bt(
    const bf16_t* __restrict__ A, const bf16_t* __restrict__ Bt,
    OutT* __restrict__ C, int M, int N, int K) {
  __shared__ __align__(16) bf16_t As[128 * 32];
  __shared__ __align__(16) bf16_t Bs[128 * 32];
  const int t = threadIdx.x;
  const int wave = t >> 6, lane = t & 63;
  const int quad = lane >> 4, l16 = lane & 15;
  const int m0 = blockIdx.y * 128, n0 = blockIdx.x * 128;
  const int wm = (wave >> 1) * 64, wn = (wave & 1) * 64;

  fragC zero4 = {0.f, 0.f, 0.f, 0.f};
  fragC acc[4][4];
#pragma unroll
  for (int i = 0; i < 4; ++i)
#pragma unroll
    for (int j = 0; j < 4; ++j) acc[i][j] = zero4;

  int rowS[2], colS[2];
#pragma unroll
  for (int i = 0; i < 2; ++i) {
    int e = (wave * 2048 + i * 1024 + lane * 16) >> 1;
    rowS[i] = e >> 5;
    colS[i] = e & 31;
  }

  for (int k0 = 0; k0 < K; k0 += 32) {
#pragma unroll
    for (int i = 0; i < 2; ++i) {
      async_copy16(A + (size_t)(m0 + rowS[i]) * K + k0 + colS[i],
                   (char*)As + wave * 2048 + i * 1024);
      async_copy16(Bt + (size_t)(n0 + rowS[i]) * K + k0 + colS[i],
                   (char*)Bs + wave * 2048 + i * 1024);
    }
    __syncthreads();
    fragAB af[4], bfr[4];
#pragma unroll
    for (int i = 0; i < 4; ++i) {
      af[i]  = *(const fragAB*)((const char*)As + (wm + i * 16 + l16) * 64 + quad * 16);
      bfr[i] = *(const fragAB*)((const char*)Bs + (wn + i * 16 + l16) * 64 + quad * 16);
    }
#pragma unroll
    for (int i = 0; i < 4; ++i)
#pragma unroll
      for (int j = 0; j < 4; ++j)
        acc[i][j] = __builtin_amdgcn_mfma_f32_16x16x32_bf16(af[i], bfr[j], acc[i][j], 0, 0, 0);
    __syncthreads();
  }

#pragma unroll
  for (int i = 0; i < 4; ++i)
#pragma unroll
    for (int j = 0; j < 4; ++j)
#pragma unroll
      for (int r = 0; r < 4; ++r) {
        int row = m0 + wm + i * 16 + quad * 4 + r;
        int col = n0 + wn + j * 16 + l16;
        float v = acc[i][j][r];
        if constexpr (sizeof(OutT) == 2)
          C[(size_t)row * N + col] = (OutT)__float2bfloat16(v);
        else
          C[(size_t)row * N + col] = (OutT)v;
      }
}

// ---------------------------------------------------------------------------
// Split-precision GEMM: C = (Ah+Al)*(Bh+Bl)^T ~ Ah*Bh + Ah*Bl + Al*Bh.
// fp32 out. Same 128x128 tile structure, 3x MFMA.
// ---------------------------------------------------------------------------
__global__ __launch_bounds__(256) void gemm_split(
    const bf16_t* __restrict__ Ah, const bf16_t* __restrict__ Al,
    const bf16_t* __restrict__ Bh, const bf16_t* __restrict__ Bl,
    float* __restrict__ C, int M, int N, int K) {
  __shared__ __align__(16) bf16_t Ash[128 * 32];
  __shared__ __align__(16) bf16_t Asl[128 * 32];
  __shared__ __align__(16) bf16_t Bsh[128 * 32];
  __shared__ __align__(16) bf16_t Bsl[128 * 32];
  const int t = threadIdx.x;
  const int wave = t >> 6, lane = t & 63;
  const int quad = lane >> 4, l16 = lane & 15;
  const int m0 = blockIdx.y * 128, n0 = blockIdx.x * 128;
  const int wm = (wave >> 1) * 64, wn = (wave & 1) * 64;

  fragC zero4 = {0.f, 0.f, 0.f, 0.f};
  fragC acc[4][4];
#pragma unroll
  for (int i = 0; i < 4; ++i)
#pragma unroll
    for (int j = 0; j < 4; ++j) acc[i][j] = zero4;

  int rowS[2], colS[2];
#pragma unroll
  for (int i = 0; i < 2; ++i) {
    int e = (wave * 2048 + i * 1024 + lane * 16) >> 1;
    rowS[i] = e >> 5;
    colS[i] = e & 31;
  }

  for (int k0 = 0; k0 < K; k0 += 32) {
#pragma unroll
    for (int i = 0; i < 2; ++i) {
      size_t offA = (size_t)(m0 + rowS[i]) * K + k0 + colS[i];
      size_t offB = (size_t)(n0 + rowS[i]) * K + k0 + colS[i];
      char* dst = (char*)0 + wave * 2048 + i * 1024;
      async_copy16(Ah + offA, (char*)Ash + (size_t)dst);
      async_copy16(Al + offA, (char*)Asl + (size_t)dst);
      async_copy16(Bh + offB, (char*)Bsh + (size_t)dst);
      async_copy16(Bl + offB, (char*)Bsl + (size_t)dst);
    }
    __syncthreads();
    fragAB ah[4], al[4], bh[4], bl[4];
#pragma unroll
    for (int i = 0; i < 4; ++i) {
      int ro = (wm + i * 16 + l16) * 64 + quad * 16;
      int co = (wn + i * 16 + l16) * 64 + quad * 16;
      ah[i] = *(const fragAB*)((const char*)Ash + ro);
      al[i] = *(const fragAB*)((const char*)Asl + ro);
      bh[i] = *(const fragAB*)((const char*)Bsh + co);
      bl[i] = *(const fragAB*)((const char*)Bsl + co);
    }
#pragma unroll
    for (int i = 0; i < 4; ++i)
#pragma unroll
      for (int j = 0; j < 4; ++j) {
        acc[i][j] = __builtin_amdgcn_mfma_f32_16x16x32_bf16(al[i], bh[j], acc[i][j], 0, 0, 0);
        acc[i][j] = __builtin_amdgcn_mfma_f32_16x16x32_bf16(ah[i], bl[j], acc[i][j], 0, 0, 0);
        acc[i][j] = __builtin_amdgcn_mfma_f32_16x16x32_bf16(ah[i], bh[j], acc[i][j], 0, 0, 0);
      }
    __syncthreads();
  }

#pragma unroll
  for (int i = 0; i < 4; ++i)
#pragma unroll
    for (int j = 0; j < 4; ++j)
#pragma unroll
      for (int r = 0; r < 4; ++r) {
        int row = m0 + wm + i * 16 + quad * 4 + r;
        int col = n0 + wn + j * 16 + l16;
        C[(size_t)row * N + col] = acc[i][j][r];
      }
}

// ---------------------------------------------------------------------------
// RMS-norm (+fp32 weight) + RoPE, fp32 in -> split bf16 hi/lo out.
// proj: [S][nheads*D] fp32
// ---------------------------------------------------------------------------
__global__ __launch_bounds__(256) void rmsnorm_rope_split(
    const float* __restrict__ proj, const float* __restrict__ w,
    const float* __restrict__ cosb, const float* __restrict__ sinb,
    bf16_t* __restrict__ qhi, bf16_t* __restrict__ qlo, int nheads) {
  int s = blockIdx.x, h = blockIdx.y, d = threadIdx.x;
  size_t idx = (size_t)s * nheads * DHEAD + h * DHEAD + d;
  float x = proj[idx];
  float ss = x * x;
  ss += __shfl_xor(ss, 1);  ss += __shfl_xor(ss, 2);  ss += __shfl_xor(ss, 4);
  ss += __shfl_xor(ss, 8);  ss += __shfl_xor(ss, 16); ss += __shfl_xor(ss, 32);
  __shared__ float part[4];
  __shared__ float xs[DHEAD];
  if ((threadIdx.x & 63) == 0) part[threadIdx.x >> 6] = ss;
  __syncthreads();
  float tot = part[0] + part[1] + part[2] + part[3];
  float r = rsqrtf(tot * (1.0f / DHEAD) + 1e-6f);
  float xn = x * r * w[d];
  xs[d] = xn;
  __syncthreads();
  float other = xs[(d + 128) & 255];
  float rot = (d < 128) ? -other : other;
  float y = xn * cosb[(size_t)s * DHEAD + d] + rot * sinb[(size_t)s * DHEAD + d];
  bf16_t h2, l2; split2(y, h2, l2);
  qhi[idx] = h2;
  qlo[idx] = l2;
}

// ---------------------------------------------------------------------------
// RMS-norm (no weight), fp32 in, bf16 out transposed: [NKV][D][S]
// ---------------------------------------------------------------------------
__global__ __launch_bounds__(256) void rmsnorm_vT(
    const float* __restrict__ proj, bf16_t* __restrict__ vt) {
  int s = blockIdx.x, h = blockIdx.y, d = threadIdx.x;
  float x = proj[(size_t)s * NKVH * DHEAD + h * DHEAD + d];
  float ss = x * x;
  ss += __shfl_xor(ss, 1);  ss += __shfl_xor(ss, 2);  ss += __shfl_xor(ss, 4);
  ss += __shfl_xor(ss, 8);  ss += __shfl_xor(ss, 16); ss += __shfl_xor(ss, 32);
  __shared__ float part[4];
  if ((threadIdx.x & 63) == 0) part[threadIdx.x >> 6] = ss;
  __syncthreads();
  float tot = part[0] + part[1] + part[2] + part[3];
  float r = rsqrtf(tot * (1.0f / DHEAD) + 1e-6f);
  vt[((size_t)h * DHEAD + d) * S_LEN + s] = __float2bfloat16(x * r);
}

// ---------------------------------------------------------------------------
// Flash attention, sliding window 512, NO score scale, GQA G=4.
// Q hi/lo: [S][NH*D], K hi/lo: [S][NKV*D], Vt: [NKV][D][S]. Out: [S][NH*D] bf16.
// QK^T via 3-term split MFMA (fp32-quality scores).
// ---------------------------------------------------------------------------
__global__ __launch_bounds__(256) void attn_split(
    const bf16_t* __restrict__ Qhi, const bf16_t* __restrict__ Qlo,
    const bf16_t* __restrict__ Khi, const bf16_t* __restrict__ Klo,
    const bf16_t* __restrict__ Vt, bf16_t* __restrict__ Aout) {
  const int h = blockIdx.y;
  const int qb = blockIdx.x * 64;
  const int wave = threadIdx.x >> 6, lane = threadIdx.x & 63;
  const int quad = lane >> 4, l16 = lane & 15;
  const int qw = qb + wave * 16;
  const int kv = h >> 2;  // G = 4
  const bf16_t* Qh_ = Qhi + h * DHEAD;   // row stride NHQ*DHEAD
  const bf16_t* Ql_ = Qlo + h * DHEAD;
  const bf16_t* Kh_ = Khi + kv * DHEAD;  // row stride NKVH*DHEAD
  const bf16_t* Kl_ = Klo + kv * DHEAD;
  const bf16_t* Vh_ = Vt + (size_t)kv * DHEAD * S_LEN;

  __shared__ __align__(16) bf16_t Plds[4][16 * 32];

  fragAB qfh[8], qfl[8];
#pragma unroll
  for (int c = 0; c < 8; ++c) {
    size_t off = (size_t)(qw + l16) * (NHQ * DHEAD) + c * 32 + quad * 8;
    qfh[c] = *(const fragAB*)(Qh_ + off);
    qfl[c] = *(const fragAB*)(Ql_ + off);
  }

  fragC zero4 = {0.f, 0.f, 0.f, 0.f};
  fragC o_acc[16];
#pragma unroll
  for (int c = 0; c < 16; ++c) o_acc[c] = zero4;
  float m_run[4] = {NEG_BIG, NEG_BIG, NEG_BIG, NEG_BIG};
  float l_run[4] = {0.f, 0.f, 0.f, 0.f};
  const float LOG2E = 1.4426950408889634f;

  int k_lo = qb - (WIN - 1);
  if (k_lo < 0) k_lo = 0;
  k_lo &= ~31;

  for (int kb = k_lo; kb < qb + 64; kb += 32) {
    fragC s0 = zero4, s1 = zero4;
#pragma unroll
    for (int c = 0; c < 8; ++c) {
      size_t o0 = (size_t)(kb + l16) * (NKVH * DHEAD) + c * 32 + quad * 8;
      size_t o1 = (size_t)(kb + 16 + l16) * (NKVH * DHEAD) + c * 32 + quad * 8;
      fragAB kh0 = *(const fragAB*)(Kh_ + o0);
      fragAB kl0 = *(const fragAB*)(Kl_ + o0);
      fragAB kh1 = *(const fragAB*)(Kh_ + o1);
      fragAB kl1 = *(const fragAB*)(Kl_ + o1);
      s0 = __builtin_amdgcn_mfma_f32_16x16x32_bf16(qfl[c], kh0, s0, 0, 0, 0);
      s0 = __builtin_amdgcn_mfma_f32_16x16x32_bf16(qfh[c], kl0, s0, 0, 0, 0);
      s0 = __builtin_amdgcn_mfma_f32_16x16x32_bf16(qfh[c], kh0, s0, 0, 0, 0);
      s1 = __builtin_amdgcn_mfma_f32_16x16x32_bf16(qfl[c], kh1, s1, 0, 0, 0);
      s1 = __builtin_amdgcn_mfma_f32_16x16x32_bf16(qfh[c], kl1, s1, 0, 0, 0);
      s1 = __builtin_amdgcn_mfma_f32_16x16x32_bf16(qfh[c], kh1, s1, 0, 0, 0);
    }
    float p0[4], p1[4], alpha[4];
#pragma unroll
    for (int r = 0; r < 4; ++r) {
      int qi = qw + quad * 4 + r;
      int k0i = kb + l16;
      int k1i = k0i + 16;
      bool v0 = (k0i <= qi) && (qi - k0i < WIN);
      bool v1 = (k1i <= qi) && (qi - k1i < WIN);
      float sv0 = v0 ? s0[r] : NEG_BIG;
      float sv1 = v1 ? s1[r] : NEG_BIG;
      float mx = fmaxf(sv0, sv1);
      mx = fmaxf(mx, __shfl_xor(mx, 1));
      mx = fmaxf(mx, __shfl_xor(mx, 2));
      mx = fmaxf(mx, __shfl_xor(mx, 4));
      mx = fmaxf(mx, __shfl_xor(mx, 8));
      float mn = fmaxf(m_run[r], mx);
      float a  = exp2f(fmaxf(m_run[r] - mn, -80.f) * LOG2E);
      float e0 = v0 ? exp2f(fmaxf(s0[r] - mn, -80.f) * LOG2E) : 0.f;
      float e1 = v1 ? exp2f(fmaxf(s1[r] - mn, -80.f) * LOG2E) : 0.f;
      float rs = e0 + e1;
      rs += __shfl_xor(rs, 1);
      rs += __shfl_xor(rs, 2);
      rs += __shfl_xor(rs, 4);
      rs += __shfl_xor(rs, 8);
      l_run[r] = l_run[r] * a + rs;
      m_run[r] = mn;
      alpha[r] = a; p0[r] = e0; p1[r] = e1;
    }
#pragma unroll
    for (int c = 0; c < 16; ++c)
#pragma unroll
      for (int r = 0; r < 4; ++r) o_acc[c][r] *= alpha[r];
    bf16_t* Pw = Plds[wave];
#pragma unroll
    for (int r = 0; r < 4; ++r) {
      Pw[(quad * 4 + r) * 32 + l16]      = __float2bfloat16(p0[r]);
      Pw[(quad * 4 + r) * 32 + 16 + l16] = __float2bfloat16(p1[r]);
    }
    __syncthreads();
    fragAB pf = *(const fragAB*)((const char*)Pw + l16 * 64 + quad * 16);
#pragma unroll
    for (int c = 0; c < 16; ++c) {
      fragAB vf = *(const fragAB*)(Vh_ + (size_t)(c * 16 + l16) * S_LEN + kb + quad * 8);
      o_acc[c] = __builtin_amdgcn_mfma_f32_16x16x32_bf16(pf, vf, o_acc[c], 0, 0, 0);
    }
    __syncthreads();
  }

  float inv_l[4];
#pragma unroll
  for (int r = 0; r < 4; ++r) inv_l[r] = 1.0f / l_run[r];
#pragma unroll
  for (int c = 0; c < 16; ++c)
#pragma unroll
    for (int r = 0; r < 4; ++r) {
      int row = qw + quad * 4 + r;
      int col = h * DHEAD + c * 16 + l16;
      Aout[(size_t)row * (NHQ * DHEAD) + col] = __float2bfloat16(o_acc[c][r] * inv_l[r]);
    }
}

// ---------------------------------------------------------------------------
extern "C" void kernel_launch(void* const* d_in, const int* in_sizes, int n_in,
                              void* d_out, int out_size, void* d_ws, size_t ws_size,
                              hipStream_t stream) {
  const float* hid  = (const float*)d_in[0];
  const float* w_q  = (const float*)d_in[1];
  const float* w_k  = (const float*)d_in[2];
  const float* w_v  = (const float*)d_in[3];
  const float* w_o  = (const float*)d_in[4];
  const float* qnw  = (const float*)d_in[5];
  const float* knw  = (const float*)d_in[6];
  const float* cosb = (const float*)d_in[7];
  const float* sinb = (const float*)d_in[8];
  float* outp = (float*)d_out;

  // Workspace layout (bf16 slots, 1M = 1<<20), peak 51M slots = 102 MiB.
  // Lifetime aliasing:
  //   [ 0:8M )  hidh   -> qh  (after q/k/v projections)
  //   [ 8:16M)  hidl   -> ql
  //   [16:32M)  qproj(f32) -> aout[16:24M) after q-norm
  //   [32:36M)  wqh    -> woT after qproj
  //   [36:40M)  wql    -> kh[36:38M), kl[38:40M) after projections
  //   [40:41M)  wkh    -> vt[40:42M) after kproj
  //   [41:42M)  wkl
  //   [42:43M)  wvT
  //   [43:47M)  kproj(f32)
  //   [47:51M)  vproj(f32)
  const size_t M1 = 1048576;
  bf16_t* w = (bf16_t*)d_ws;
  bf16_t* hidh  = w;
  bf16_t* qh    = w;                         // aliases hidh
  bf16_t* hidl  = w + 8 * M1;
  bf16_t* ql    = w + 8 * M1;                // aliases hidl
  float*  qproj = (float*)(w + 16 * M1);
  bf16_t* aout  = w + 16 * M1;               // aliases qproj
  bf16_t* wqh   = w + 32 * M1;
  bf16_t* woT   = w + 32 * M1;               // aliases wqh
  bf16_t* wql   = w + 36 * M1;
  bf16_t* kh    = w + 36 * M1;               // aliases wql
  bf16_t* kl    = w + 38 * M1;
  bf16_t* wkh   = w + 40 * M1;
  bf16_t* vt    = w + 40 * M1;               // aliases wkh+wkl
  bf16_t* wkl   = w + 41 * M1;
  bf16_t* wvT   = w + 42 * M1;
  float*  kproj = (float*)(w + 43 * M1);
  float*  vproj = (float*)(w + 47 * M1);

  // phase 0: split hidden; split-transpose wq/wk; plain-transpose wv
  split_f32<<<(S_LEN * HDIM) / 1024, 256, 0, stream>>>(hid, hidh, hidl, S_LEN * HDIM);
  transpose_split<<<dim3((NHQ * DHEAD) / 32, HDIM / 32), 256, 0, stream>>>(w_q, wqh, wql, HDIM, NHQ * DHEAD);
  transpose_split<<<dim3((NKVH * DHEAD) / 32, HDIM / 32), 256, 0, stream>>>(w_k, wkh, wkl, HDIM, NKVH * DHEAD);
  transpose_cvt<<<dim3((NKVH * DHEAD) / 32, HDIM / 32), 256, 0, stream>>>(w_v, wvT, HDIM, NKVH * DHEAD);

  // phase 1: projections (q/k split-precision fp32 out; v plain fp32 out)
  gemm_split<<<dim3((NHQ * DHEAD) / 128, S_LEN / 128), 256, 0, stream>>>(hidh, hidl, wqh, wql, qproj, S_LEN, NHQ * DHEAD, HDIM);
  gemm_split<<<dim3((NKVH * DHEAD) / 128, S_LEN / 128), 256, 0, stream>>>(hidh, hidl, wkh, wkl, kproj, S_LEN, NKVH * DHEAD, HDIM);
  gemm_bt<float><<<dim3((NKVH * DHEAD) / 128, S_LEN / 128), 256, 0, stream>>>(hidh, wvT, vproj, S_LEN, NKVH * DHEAD, HDIM);

  // phase 2: norms (fp32) -> split q/k; v -> bf16 transposed
  rmsnorm_rope_split<<<dim3(S_LEN, NHQ), 256, 0, stream>>>(qproj, qnw, cosb, sinb, qh, ql, NHQ);
  rmsnorm_rope_split<<<dim3(S_LEN, NKVH), 256, 0, stream>>>(kproj, knw, cosb, sinb, kh, kl, NKVH);
  rmsnorm_vT<<<dim3(S_LEN, NKVH), 256, 0, stream>>>(vproj, vt);

  // phase 3: w_o transpose (wqh dead)
  transpose_cvt<<<dim3(HDIM / 32, (NHQ * DHEAD) / 32), 256, 0, stream>>>(w_o, woT, NHQ * DHEAD, HDIM);

  // phase 4: attention (qproj dead -> aout)
  attn_split<<<dim3(S_LEN / 64, NHQ), 256, 0, stream>>>(qh, ql, kh, kl, vt, aout);

  // phase 5: output projection -> fp32 d_out
  gemm_bt<float><<<dim3(HDIM / 128, S_LEN / 128), 256, 0, stream>>>(aout, woT, outp, S_LEN, HDIM, NHQ * DHEAD);
}

// Round 6
// 573.129 us; speedup vs baseline: 1.2542x; 1.2542x over previous
//
#include <hip/hip_runtime.h>
#include <hip/hip_bf16.h>

#define S_LEN 4096
#define HDIM  2048
#define NHQ   8
#define NKVH  2
#define DHEAD 256
#define WIN   512

typedef __hip_bfloat16 bf16_t;
using fragAB = __attribute__((ext_vector_type(8))) short;  // 8 bf16
using fragC  = __attribute__((ext_vector_type(4))) float;  // 4 fp32

typedef unsigned int u32;
typedef const __attribute__((address_space(1))) u32* gas_ptr;
typedef __attribute__((address_space(3))) u32* las_ptr;

__device__ __forceinline__ void async_copy16(const void* g, void* l) {
  __builtin_amdgcn_global_load_lds((gas_ptr)g, (las_ptr)l, 16, 0, 0);
}

#define NEG_BIG (-3.0e38f)

__device__ __forceinline__ void split2(float x, bf16_t& hi, bf16_t& lo) {
  bf16_t h = __float2bfloat16(x);
  hi = h;
  lo = __float2bfloat16(x - (float)h);
}

// ---------------------------------------------------------------------------
// Elementwise split fp32 -> bf16 hi + bf16 lo  (n multiple of 1024)
// ---------------------------------------------------------------------------
__global__ __launch_bounds__(256) void split_f32(
    const float* __restrict__ in, bf16_t* __restrict__ hi,
    bf16_t* __restrict__ lo, int n) {
  int i = (blockIdx.x * 256 + threadIdx.x) * 4;
  if (i >= n) return;
  float4 v = *(const float4*)(in + i);
  split2(v.x, hi[i + 0], lo[i + 0]);
  split2(v.y, hi[i + 1], lo[i + 1]);
  split2(v.z, hi[i + 2], lo[i + 2]);
  split2(v.w, hi[i + 3], lo[i + 3]);
}

// ---------------------------------------------------------------------------
// Transpose+convert fp32 [R][C] -> bf16 [C][R]
// ---------------------------------------------------------------------------
__global__ __launch_bounds__(256) void transpose_cvt(
    const float* __restrict__ in, bf16_t* __restrict__ out, int R, int C) {
  __shared__ bf16_t tile[32][33];
  int c0 = blockIdx.x * 32, r0 = blockIdx.y * 32;
  int tx = threadIdx.x & 31, ty = threadIdx.x >> 5;
#pragma unroll
  for (int i = 0; i < 4; ++i)
    tile[ty + i * 8][tx] = __float2bfloat16(in[(size_t)(r0 + ty + i * 8) * C + c0 + tx]);
  __syncthreads();
#pragma unroll
  for (int i = 0; i < 4; ++i)
    out[(size_t)(c0 + ty + i * 8) * R + r0 + tx] = tile[tx][ty + i * 8];
}

// ---------------------------------------------------------------------------
// Transpose+split fp32 [R][C] -> bf16 hi [C][R], bf16 lo [C][R]
// ---------------------------------------------------------------------------
__global__ __launch_bounds__(256) void transpose_split(
    const float* __restrict__ in, bf16_t* __restrict__ hiT,
    bf16_t* __restrict__ loT, int R, int C) {
  __shared__ bf16_t th[32][33];
  __shared__ bf16_t tl[32][33];
  int c0 = blockIdx.x * 32, r0 = blockIdx.y * 32;
  int tx = threadIdx.x & 31, ty = threadIdx.x >> 5;
#pragma unroll
  for (int i = 0; i < 4; ++i) {
    float x = in[(size_t)(r0 + ty + i * 8) * C + c0 + tx];
    bf16_t h, l; split2(x, h, l);
    th[ty + i * 8][tx] = h;
    tl[ty + i * 8][tx] = l;
  }
  __syncthreads();
#pragma unroll
  for (int i = 0; i < 4; ++i) {
    hiT[(size_t)(c0 + ty + i * 8) * R + r0 + tx] = th[tx][ty + i * 8];
    loT[(size_t)(c0 + ty + i * 8) * R + r0 + tx] = tl[tx][ty + i * 8];
  }
}

// ---------------------------------------------------------------------------
// Plain GEMM: C[M][N] = A[M][K]*Bt[N][K]^T; bf16 in, fp32 accum, OutT out.
// ---------------------------------------------------------------------------
template <typename OutT>
__global__ __launch_bounds__(256) void gemm_bt(
    const bf16_t* __restrict__ A, const bf16_t* __restrict__ Bt,
    OutT* __restrict__ C, int M, int N, int K) {
  __shared__ __align__(16) bf16_t As[128 * 32];
  __shared__ __align__(16) bf16_t Bs[128 * 32];
  const int t = threadIdx.x;
  const int wave = t >> 6, lane = t & 63;
  const int quad = lane >> 4, l16 = lane & 15;
  const int m0 = blockIdx.y * 128, n0 = blockIdx.x * 128;
  const int wm = (wave >> 1) * 64, wn = (wave & 1) * 64;

  fragC zero4 = {0.f, 0.f, 0.f, 0.f};
  fragC acc[4][4];
#pragma unroll
  for (int i = 0; i < 4; ++i)
#pragma unroll
    for (int j = 0; j < 4; ++j) acc[i][j] = zero4;

  int rowS[2], colS[2];
#pragma unroll
  for (int i = 0; i < 2; ++i) {
    int e = (wave * 2048 + i * 1024 + lane * 16) >> 1;
    rowS[i] = e >> 5;
    colS[i] = e & 31;
  }

  for (int k0 = 0; k0 < K; k0 += 32) {
#pragma unroll
    for (int i = 0; i < 2; ++i) {
      async_copy16(A + (size_t)(m0 + rowS[i]) * K + k0 + colS[i],
                   (char*)As + wave * 2048 + i * 1024);
      async_copy16(Bt + (size_t)(n0 + rowS[i]) * K + k0 + colS[i],
                   (char*)Bs + wave * 2048 + i * 1024);
    }
    __syncthreads();
    fragAB af[4], bfr[4];
#pragma unroll
    for (int i = 0; i < 4; ++i) {
      af[i]  = *(const fragAB*)((const char*)As + (wm + i * 16 + l16) * 64 + quad * 16);
      bfr[i] = *(const fragAB*)((const char*)Bs + (wn + i * 16 + l16) * 64 + quad * 16);
    }
#pragma unroll
    for (int i = 0; i < 4; ++i)
#pragma unroll
      for (int j = 0; j < 4; ++j)
        acc[i][j] = __builtin_amdgcn_mfma_f32_16x16x32_bf16(af[i], bfr[j], acc[i][j], 0, 0, 0);
    __syncthreads();
  }

#pragma unroll
  for (int i = 0; i < 4; ++i)
#pragma unroll
    for (int j = 0; j < 4; ++j)
#pragma unroll
      for (int r = 0; r < 4; ++r) {
        int row = m0 + wm + i * 16 + quad * 4 + r;
        int col = n0 + wn + j * 16 + l16;
        float v = acc[i][j][r];
        if constexpr (sizeof(OutT) == 2)
          C[(size_t)row * N + col] = (OutT)__float2bfloat16(v);
        else
          C[(size_t)row * N + col] = (OutT)v;
      }
}

// ---------------------------------------------------------------------------
// Split-precision GEMM: C = (Ah+Al)*(Bh+Bl)^T ~ Ah*Bh + Ah*Bl + Al*Bh.
// ---------------------------------------------------------------------------
__global__ __launch_bounds__(256) void gemm_split(
    const bf16_t* __restrict__ Ah, const bf16_t* __restrict__ Al,
    const bf16_t* __restrict__ Bh, const bf16_t* __restrict__ Bl,
    float* __restrict__ C, int M, int N, int K) {
  __shared__ __align__(16) bf16_t Ash[128 * 32];
  __shared__ __align__(16) bf16_t Asl[128 * 32];
  __shared__ __align__(16) bf16_t Bsh[128 * 32];
  __shared__ __align__(16) bf16_t Bsl[128 * 32];
  const int t = threadIdx.x;
  const int wave = t >> 6, lane = t & 63;
  const int quad = lane >> 4, l16 = lane & 15;
  const int m0 = blockIdx.y * 128, n0 = blockIdx.x * 128;
  const int wm = (wave >> 1) * 64, wn = (wave & 1) * 64;

  fragC zero4 = {0.f, 0.f, 0.f, 0.f};
  fragC acc[4][4];
#pragma unroll
  for (int i = 0; i < 4; ++i)
#pragma unroll
    for (int j = 0; j < 4; ++j) acc[i][j] = zero4;

  int rowS[2], colS[2];
#pragma unroll
  for (int i = 0; i < 2; ++i) {
    int e = (wave * 2048 + i * 1024 + lane * 16) >> 1;
    rowS[i] = e >> 5;
    colS[i] = e & 31;
  }

  for (int k0 = 0; k0 < K; k0 += 32) {
#pragma unroll
    for (int i = 0; i < 2; ++i) {
      size_t offA = (size_t)(m0 + rowS[i]) * K + k0 + colS[i];
      size_t offB = (size_t)(n0 + rowS[i]) * K + k0 + colS[i];
      size_t dst = wave * 2048 + i * 1024;
      async_copy16(Ah + offA, (char*)Ash + dst);
      async_copy16(Al + offA, (char*)Asl + dst);
      async_copy16(Bh + offB, (char*)Bsh + dst);
      async_copy16(Bl + offB, (char*)Bsl + dst);
    }
    __syncthreads();
    fragAB ah[4], al[4], bh[4], bl[4];
#pragma unroll
    for (int i = 0; i < 4; ++i) {
      int ro = (wm + i * 16 + l16) * 64 + quad * 16;
      int co = (wn + i * 16 + l16) * 64 + quad * 16;
      ah[i] = *(const fragAB*)((const char*)Ash + ro);
      al[i] = *(const fragAB*)((const char*)Asl + ro);
      bh[i] = *(const fragAB*)((const char*)Bsh + co);
      bl[i] = *(const fragAB*)((const char*)Bsl + co);
    }
#pragma unroll
    for (int i = 0; i < 4; ++i)
#pragma unroll
      for (int j = 0; j < 4; ++j) {
        acc[i][j] = __builtin_amdgcn_mfma_f32_16x16x32_bf16(al[i], bh[j], acc[i][j], 0, 0, 0);
        acc[i][j] = __builtin_amdgcn_mfma_f32_16x16x32_bf16(ah[i], bl[j], acc[i][j], 0, 0, 0);
        acc[i][j] = __builtin_amdgcn_mfma_f32_16x16x32_bf16(ah[i], bh[j], acc[i][j], 0, 0, 0);
      }
    __syncthreads();
  }

#pragma unroll
  for (int i = 0; i < 4; ++i)
#pragma unroll
    for (int j = 0; j < 4; ++j)
#pragma unroll
      for (int r = 0; r < 4; ++r) {
        int row = m0 + wm + i * 16 + quad * 4 + r;
        int col = n0 + wn + j * 16 + l16;
        C[(size_t)row * N + col] = acc[i][j][r];
      }
}

// ---------------------------------------------------------------------------
// RMS-norm (+fp32 weight) + RoPE, fp32 in -> split bf16 hi/lo out.
// ---------------------------------------------------------------------------
__global__ __launch_bounds__(256) void rmsnorm_rope_split(
    const float* __restrict__ proj, const float* __restrict__ w,
    const float* __restrict__ cosb, const float* __restrict__ sinb,
    bf16_t* __restrict__ qhi, bf16_t* __restrict__ qlo, int nheads) {
  int s = blockIdx.x, h = blockIdx.y, d = threadIdx.x;
  size_t idx = (size_t)s * nheads * DHEAD + h * DHEAD + d;
  float x = proj[idx];
  float ss = x * x;
  ss += __shfl_xor(ss, 1);  ss += __shfl_xor(ss, 2);  ss += __shfl_xor(ss, 4);
  ss += __shfl_xor(ss, 8);  ss += __shfl_xor(ss, 16); ss += __shfl_xor(ss, 32);
  __shared__ float part[4];
  __shared__ float xs[DHEAD];
  if ((threadIdx.x & 63) == 0) part[threadIdx.x >> 6] = ss;
  __syncthreads();
  float tot = part[0] + part[1] + part[2] + part[3];
  float r = rsqrtf(tot * (1.0f / DHEAD) + 1e-6f);
  float xn = x * r * w[d];
  xs[d] = xn;
  __syncthreads();
  float other = xs[(d + 128) & 255];
  float rot = (d < 128) ? -other : other;
  float y = xn * cosb[(size_t)s * DHEAD + d] + rot * sinb[(size_t)s * DHEAD + d];
  bf16_t h2, l2; split2(y, h2, l2);
  qhi[idx] = h2;
  qlo[idx] = l2;
}

// ---------------------------------------------------------------------------
// RMS-norm (no weight), fp32 in, bf16 out transposed: [NKV][D][S]
// ---------------------------------------------------------------------------
__global__ __launch_bounds__(256) void rmsnorm_vT(
    const float* __restrict__ proj, bf16_t* __restrict__ vt) {
  int s = blockIdx.x, h = blockIdx.y, d = threadIdx.x;
  float x = proj[(size_t)s * NKVH * DHEAD + h * DHEAD + d];
  float ss = x * x;
  ss += __shfl_xor(ss, 1);  ss += __shfl_xor(ss, 2);  ss += __shfl_xor(ss, 4);
  ss += __shfl_xor(ss, 8);  ss += __shfl_xor(ss, 16); ss += __shfl_xor(ss, 32);
  __shared__ float part[4];
  if ((threadIdx.x & 63) == 0) part[threadIdx.x >> 6] = ss;
  __syncthreads();
  float tot = part[0] + part[1] + part[2] + part[3];
  float r = rsqrtf(tot * (1.0f / DHEAD) + 1e-6f);
  vt[((size_t)h * DHEAD + d) * S_LEN + s] = __float2bfloat16(x * r);
}

// ---------------------------------------------------------------------------
// Flash attention, sliding window 512, NO score scale, GQA G=4.
// K/V staged in LDS per 32-key step (global_load_lds w=16), shared by all
// 4 waves. XOR source-swizzle makes ds_read_b128 fragment fetches 2-way
// (conflict-free): LDS chunk (row r, chunk c) holds global chunk (c ^ r).
// ---------------------------------------------------------------------------
__global__ __launch_bounds__(256) void attn_split(
    const bf16_t* __restrict__ Qhi, const bf16_t* __restrict__ Qlo,
    const bf16_t* __restrict__ Khi, const bf16_t* __restrict__ Klo,
    const bf16_t* __restrict__ Vt, bf16_t* __restrict__ Aout) {
  const int h = blockIdx.y;
  const int qb = blockIdx.x * 64;
  const int wave = threadIdx.x >> 6, lane = threadIdx.x & 63;
  const int quad = lane >> 4, l16 = lane & 15;
  const int qw = qb + wave * 16;
  const int kv = h >> 2;  // G = 4
  const bf16_t* Qh_ = Qhi + h * DHEAD;   // row stride NHQ*DHEAD
  const bf16_t* Ql_ = Qlo + h * DHEAD;
  const bf16_t* Kh_ = Khi + kv * DHEAD;  // row stride NKVH*DHEAD
  const bf16_t* Kl_ = Klo + kv * DHEAD;
  const bf16_t* Vh_ = Vt + (size_t)kv * DHEAD * S_LEN;

  // K tiles: 32 keys x 256 dims (16 KB each, 32 chunks/row of 16B)
  // V tile: 256 dims x 32 keys (16 KB, 4 chunks/row of 16B)
  __shared__ __align__(16) bf16_t KshH[32 * 256];
  __shared__ __align__(16) bf16_t KshL[32 * 256];
  __shared__ __align__(16) bf16_t Vsh[256 * 32];
  __shared__ __align__(16) bf16_t Plds[4][16 * 32];

  fragAB qfh[8], qfl[8];
#pragma unroll
  for (int c = 0; c < 8; ++c) {
    size_t off = (size_t)(qw + l16) * (NHQ * DHEAD) + c * 32 + quad * 8;
    qfh[c] = *(const fragAB*)(Qh_ + off);
    qfl[c] = *(const fragAB*)(Ql_ + off);
  }

  // Per-lane staging source indices (swizzled), dst base per wave-iter.
  int kRow[4], kCol[4], vRow[4], vCol[4];
#pragma unroll
  for (int i = 0; i < 4; ++i) {
    int ci = (i * 4 + wave) * 64 + lane;
    int r = ci >> 5, sc = ci & 31;
    kRow[i] = r;
    kCol[i] = (sc ^ r) * 8;            // element offset within key row
    int rv = ci >> 2, scv = ci & 3;
    vRow[i] = rv;
    vCol[i] = (scv ^ (rv & 3)) * 8;    // element offset within d row
  }

  fragC zero4 = {0.f, 0.f, 0.f, 0.f};
  fragC o_acc[16];
#pragma unroll
  for (int c = 0; c < 16; ++c) o_acc[c] = zero4;
  float m_run[4] = {NEG_BIG, NEG_BIG, NEG_BIG, NEG_BIG};
  float l_run[4] = {0.f, 0.f, 0.f, 0.f};
  const float LOG2E = 1.4426950408889634f;

  int k_lo = qb - (WIN - 1);
  if (k_lo < 0) k_lo = 0;
  k_lo &= ~31;

  for (int kb = k_lo; kb < qb + 64; kb += 32) {
    // ---- stage K hi/lo + V into LDS (swizzled source) ----
#pragma unroll
    for (int i = 0; i < 4; ++i) {
      size_t dst = (size_t)(i * 4 + wave) * 1024;
      size_t koff = (size_t)(kb + kRow[i]) * (NKVH * DHEAD) + kCol[i];
      async_copy16(Kh_ + koff, (char*)KshH + dst);
      async_copy16(Kl_ + koff, (char*)KshL + dst);
      async_copy16(Vh_ + (size_t)vRow[i] * S_LEN + kb + vCol[i], (char*)Vsh + dst);
    }
    __syncthreads();

    // ---- QK^T from LDS (3-term split) ----
    fragC s0 = zero4, s1 = zero4;
#pragma unroll
    for (int c = 0; c < 8; ++c) {
      int j = c * 4 + quad;
      int off0 = (l16 * 32 + (j ^ l16)) * 16;                    // bytes
      int off1 = ((16 + l16) * 32 + (j ^ (16 + l16))) * 16;
      fragAB kh0 = *(const fragAB*)((const char*)KshH + off0);
      fragAB kl0 = *(const fragAB*)((const char*)KshL + off0);
      fragAB kh1 = *(const fragAB*)((const char*)KshH + off1);
      fragAB kl1 = *(const fragAB*)((const char*)KshL + off1);
      s0 = __builtin_amdgcn_mfma_f32_16x16x32_bf16(qfl[c], kh0, s0, 0, 0, 0);
      s0 = __builtin_amdgcn_mfma_f32_16x16x32_bf16(qfh[c], kl0, s0, 0, 0, 0);
      s0 = __builtin_amdgcn_mfma_f32_16x16x32_bf16(qfh[c], kh0, s0, 0, 0, 0);
      s1 = __builtin_amdgcn_mfma_f32_16x16x32_bf16(qfl[c], kh1, s1, 0, 0, 0);
      s1 = __builtin_amdgcn_mfma_f32_16x16x32_bf16(qfh[c], kl1, s1, 0, 0, 0);
      s1 = __builtin_amdgcn_mfma_f32_16x16x32_bf16(qfh[c], kh1, s1, 0, 0, 0);
    }

    // ---- online softmax ----
    float p0[4], p1[4], alpha[4];
#pragma unroll
    for (int r = 0; r < 4; ++r) {
      int qi = qw + quad * 4 + r;
      int k0i = kb + l16;
      int k1i = k0i + 16;
      bool v0 = (k0i <= qi) && (qi - k0i < WIN);
      bool v1 = (k1i <= qi) && (qi - k1i < WIN);
      float sv0 = v0 ? s0[r] : NEG_BIG;
      float sv1 = v1 ? s1[r] : NEG_BIG;
      float mx = fmaxf(sv0, sv1);
      mx = fmaxf(mx, __shfl_xor(mx, 1));
      mx = fmaxf(mx, __shfl_xor(mx, 2));
      mx = fmaxf(mx, __shfl_xor(mx, 4));
      mx = fmaxf(mx, __shfl_xor(mx, 8));
      float mn = fmaxf(m_run[r], mx);
      float a  = exp2f(fmaxf(m_run[r] - mn, -80.f) * LOG2E);
      float e0 = v0 ? exp2f(fmaxf(s0[r] - mn, -80.f) * LOG2E) : 0.f;
      float e1 = v1 ? exp2f(fmaxf(s1[r] - mn, -80.f) * LOG2E) : 0.f;
      float rs = e0 + e1;
      rs += __shfl_xor(rs, 1);
      rs += __shfl_xor(rs, 2);
      rs += __shfl_xor(rs, 4);
      rs += __shfl_xor(rs, 8);
      l_run[r] = l_run[r] * a + rs;
      m_run[r] = mn;
      alpha[r] = a; p0[r] = e0; p1[r] = e1;
    }
#pragma unroll
    for (int c = 0; c < 16; ++c)
#pragma unroll
      for (int r = 0; r < 4; ++r) o_acc[c][r] *= alpha[r];

    // ---- P C-layout -> A-layout via wave-private LDS (intra-wave DS order) ----
    bf16_t* Pw = Plds[wave];
#pragma unroll
    for (int r = 0; r < 4; ++r) {
      Pw[(quad * 4 + r) * 32 + l16]      = __float2bfloat16(p0[r]);
      Pw[(quad * 4 + r) * 32 + 16 + l16] = __float2bfloat16(p1[r]);
    }
    fragAB pf = *(const fragAB*)((const char*)Pw + l16 * 64 + quad * 16);

    // ---- P*V from LDS ----
#pragma unroll
    for (int c = 0; c < 16; ++c) {
      int d = c * 16 + l16;
      int offv = (d * 4 + (quad ^ (d & 3))) * 16;                // bytes
      fragAB vf = *(const fragAB*)((const char*)Vsh + offv);
      o_acc[c] = __builtin_amdgcn_mfma_f32_16x16x32_bf16(pf, vf, o_acc[c], 0, 0, 0);
    }
    __syncthreads();  // all reads done before next staging overwrites
  }

  float inv_l[4];
#pragma unroll
  for (int r = 0; r < 4; ++r) inv_l[r] = 1.0f / l_run[r];
#pragma unroll
  for (int c = 0; c < 16; ++c)
#pragma unroll
    for (int r = 0; r < 4; ++r) {
      int row = qw + quad * 4 + r;
      int col = h * DHEAD + c * 16 + l16;
      Aout[(size_t)row * (NHQ * DHEAD) + col] = __float2bfloat16(o_acc[c][r] * inv_l[r]);
    }
}

// ---------------------------------------------------------------------------
extern "C" void kernel_launch(void* const* d_in, const int* in_sizes, int n_in,
                              void* d_out, int out_size, void* d_ws, size_t ws_size,
                              hipStream_t stream) {
  const float* hid  = (const float*)d_in[0];
  const float* w_q  = (const float*)d_in[1];
  const float* w_k  = (const float*)d_in[2];
  const float* w_v  = (const float*)d_in[3];
  const float* w_o  = (const float*)d_in[4];
  const float* qnw  = (const float*)d_in[5];
  const float* knw  = (const float*)d_in[6];
  const float* cosb = (const float*)d_in[7];
  const float* sinb = (const float*)d_in[8];
  float* outp = (float*)d_out;

  const size_t M1 = 1048576;
  bf16_t* w = (bf16_t*)d_ws;
  bf16_t* hidh  = w;
  bf16_t* qh    = w;                         // aliases hidh
  bf16_t* hidl  = w + 8 * M1;
  bf16_t* ql    = w + 8 * M1;                // aliases hidl
  float*  qproj = (float*)(w + 16 * M1);
  bf16_t* aout  = w + 16 * M1;               // aliases qproj
  bf16_t* wqh   = w + 32 * M1;
  bf16_t* woT   = w + 32 * M1;               // aliases wqh
  bf16_t* wql   = w + 36 * M1;
  bf16_t* kh    = w + 36 * M1;               // aliases wql
  bf16_t* kl    = w + 38 * M1;
  bf16_t* wkh   = w + 40 * M1;
  bf16_t* vt    = w + 40 * M1;               // aliases wkh+wkl
  bf16_t* wkl   = w + 41 * M1;
  bf16_t* wvT   = w + 42 * M1;
  float*  kproj = (float*)(w + 43 * M1);
  float*  vproj = (float*)(w + 47 * M1);

  // phase 0: split hidden; split-transpose wq/wk; plain-transpose wv
  split_f32<<<(S_LEN * HDIM) / 1024, 256, 0, stream>>>(hid, hidh, hidl, S_LEN * HDIM);
  transpose_split<<<dim3((NHQ * DHEAD) / 32, HDIM / 32), 256, 0, stream>>>(w_q, wqh, wql, HDIM, NHQ * DHEAD);
  transpose_split<<<dim3((NKVH * DHEAD) / 32, HDIM / 32), 256, 0, stream>>>(w_k, wkh, wkl, HDIM, NKVH * DHEAD);
  transpose_cvt<<<dim3((NKVH * DHEAD) / 32, HDIM / 32), 256, 0, stream>>>(w_v, wvT, HDIM, NKVH * DHEAD);

  // phase 1: projections (q/k split-precision fp32 out; v plain fp32 out)
  gemm_split<<<dim3((NHQ * DHEAD) / 128, S_LEN / 128), 256, 0, stream>>>(hidh, hidl, wqh, wql, qproj, S_LEN, NHQ * DHEAD, HDIM);
  gemm_split<<<dim3((NKVH * DHEAD) / 128, S_LEN / 128), 256, 0, stream>>>(hidh, hidl, wkh, wkl, kproj, S_LEN, NKVH * DHEAD, HDIM);
  gemm_bt<float><<<dim3((NKVH * DHEAD) / 128, S_LEN / 128), 256, 0, stream>>>(hidh, wvT, vproj, S_LEN, NKVH * DHEAD, HDIM);

  // phase 2: norms (fp32) -> split q/k; v -> bf16 transposed
  rmsnorm_rope_split<<<dim3(S_LEN, NHQ), 256, 0, stream>>>(qproj, qnw, cosb, sinb, qh, ql, NHQ);
  rmsnorm_rope_split<<<dim3(S_LEN, NKVH), 256, 0, stream>>>(kproj, knw, cosb, sinb, kh, kl, NKVH);
  rmsnorm_vT<<<dim3(S_LEN, NKVH), 256, 0, stream>>>(vproj, vt);

  // phase 3: w_o transpose (wqh dead)
  transpose_cvt<<<dim3(HDIM / 32, (NHQ * DHEAD) / 32), 256, 0, stream>>>(w_o, woT, NHQ * DHEAD, HDIM);

  // phase 4: attention (qproj dead -> aout)
  attn_split<<<dim3(S_LEN / 64, NHQ), 256, 0, stream>>>(qh, ql, kh, kl, vt, aout);

  // phase 5: output projection -> fp32 d_out
  gemm_bt<float><<<dim3(HDIM / 128, S_LEN / 128), 256, 0, stream>>>(aout, woT, outp, S_LEN, HDIM, NHQ * DHEAD);
}

// Round 7
// 564.000 us; speedup vs baseline: 1.2745x; 1.0162x over previous
//
#include <hip/hip_runtime.h>
#include <hip/hip_bf16.h>

#define S_LEN 4096
#define HDIM  2048
#define NHQ   8
#define NKVH  2
#define DHEAD 256
#define WIN   512
#define NQK   2560   // fused q+k projection width (2048 + 512)

typedef __hip_bfloat16 bf16_t;
using fragAB = __attribute__((ext_vector_type(8))) short;  // 8 bf16
using fragC  = __attribute__((ext_vector_type(4))) float;  // 4 fp32

typedef unsigned int u32;
typedef const __attribute__((address_space(1))) u32* gas_ptr;
typedef __attribute__((address_space(3))) u32* las_ptr;

__device__ __forceinline__ void async_copy16(const void* g, void* l) {
  __builtin_amdgcn_global_load_lds((gas_ptr)g, (las_ptr)l, 16, 0, 0);
}

#define NEG_BIG (-3.0e38f)

__device__ __forceinline__ void split2(float x, bf16_t& hi, bf16_t& lo) {
  bf16_t h = __float2bfloat16(x);
  hi = h;
  lo = __float2bfloat16(x - (float)h);
}

// ---------------------------------------------------------------------------
// Elementwise split fp32 -> bf16 hi + bf16 lo  (n multiple of 1024)
// ---------------------------------------------------------------------------
__global__ __launch_bounds__(256) void split_f32(
    const float* __restrict__ in, bf16_t* __restrict__ hi,
    bf16_t* __restrict__ lo, int n) {
  int i = (blockIdx.x * 256 + threadIdx.x) * 4;
  if (i >= n) return;
  float4 v = *(const float4*)(in + i);
  split2(v.x, hi[i + 0], lo[i + 0]);
  split2(v.y, hi[i + 1], lo[i + 1]);
  split2(v.z, hi[i + 2], lo[i + 2]);
  split2(v.w, hi[i + 3], lo[i + 3]);
}

// ---------------------------------------------------------------------------
// Transpose+convert fp32 [R][C] -> bf16 [C][R]
// ---------------------------------------------------------------------------
__global__ __launch_bounds__(256) void transpose_cvt(
    const float* __restrict__ in, bf16_t* __restrict__ out, int R, int C) {
  __shared__ bf16_t tile[32][33];
  int c0 = blockIdx.x * 32, r0 = blockIdx.y * 32;
  int tx = threadIdx.x & 31, ty = threadIdx.x >> 5;
#pragma unroll
  for (int i = 0; i < 4; ++i)
    tile[ty + i * 8][tx] = __float2bfloat16(in[(size_t)(r0 + ty + i * 8) * C + c0 + tx]);
  __syncthreads();
#pragma unroll
  for (int i = 0; i < 4; ++i)
    out[(size_t)(c0 + ty + i * 8) * R + r0 + tx] = tile[tx][ty + i * 8];
}

// ---------------------------------------------------------------------------
// Transpose+split fp32 [R][C] -> bf16 hi [C][R], bf16 lo [C][R]
// ---------------------------------------------------------------------------
__global__ __launch_bounds__(256) void transpose_split(
    const float* __restrict__ in, bf16_t* __restrict__ hiT,
    bf16_t* __restrict__ loT, int R, int C) {
  __shared__ bf16_t th[32][33];
  __shared__ bf16_t tl[32][33];
  int c0 = blockIdx.x * 32, r0 = blockIdx.y * 32;
  int tx = threadIdx.x & 31, ty = threadIdx.x >> 5;
#pragma unroll
  for (int i = 0; i < 4; ++i) {
    float x = in[(size_t)(r0 + ty + i * 8) * C + c0 + tx];
    bf16_t h, l; split2(x, h, l);
    th[ty + i * 8][tx] = h;
    tl[ty + i * 8][tx] = l;
  }
  __syncthreads();
#pragma unroll
  for (int i = 0; i < 4; ++i) {
    hiT[(size_t)(c0 + ty + i * 8) * R + r0 + tx] = th[tx][ty + i * 8];
    loT[(size_t)(c0 + ty + i * 8) * R + r0 + tx] = tl[tx][ty + i * 8];
  }
}

// ---------------------------------------------------------------------------
// Plain GEMM: C[M][N] = A[M][K]*Bt[N][K]^T; bf16 in, fp32 accum, OutT out.
// ---------------------------------------------------------------------------
template <typename OutT>
__global__ __launch_bounds__(256) void gemm_bt(
    const bf16_t* __restrict__ A, const bf16_t* __restrict__ Bt,
    OutT* __restrict__ C, int M, int N, int K) {
  __shared__ __align__(16) bf16_t As[128 * 32];
  __shared__ __align__(16) bf16_t Bs[128 * 32];
  const int t = threadIdx.x;
  const int wave = t >> 6, lane = t & 63;
  const int quad = lane >> 4, l16 = lane & 15;
  const int m0 = blockIdx.y * 128, n0 = blockIdx.x * 128;
  const int wm = (wave >> 1) * 64, wn = (wave & 1) * 64;

  fragC zero4 = {0.f, 0.f, 0.f, 0.f};
  fragC acc[4][4];
#pragma unroll
  for (int i = 0; i < 4; ++i)
#pragma unroll
    for (int j = 0; j < 4; ++j) acc[i][j] = zero4;

  int rowS[2], colS[2];
#pragma unroll
  for (int i = 0; i < 2; ++i) {
    int e = (wave * 2048 + i * 1024 + lane * 16) >> 1;
    rowS[i] = e >> 5;
    colS[i] = e & 31;
  }

  for (int k0 = 0; k0 < K; k0 += 32) {
#pragma unroll
    for (int i = 0; i < 2; ++i) {
      async_copy16(A + (size_t)(m0 + rowS[i]) * K + k0 + colS[i],
                   (char*)As + wave * 2048 + i * 1024);
      async_copy16(Bt + (size_t)(n0 + rowS[i]) * K + k0 + colS[i],
                   (char*)Bs + wave * 2048 + i * 1024);
    }
    __syncthreads();
    fragAB af[4], bfr[4];
#pragma unroll
    for (int i = 0; i < 4; ++i) {
      af[i]  = *(const fragAB*)((const char*)As + (wm + i * 16 + l16) * 64 + quad * 16);
      bfr[i] = *(const fragAB*)((const char*)Bs + (wn + i * 16 + l16) * 64 + quad * 16);
    }
#pragma unroll
    for (int i = 0; i < 4; ++i)
#pragma unroll
      for (int j = 0; j < 4; ++j)
        acc[i][j] = __builtin_amdgcn_mfma_f32_16x16x32_bf16(af[i], bfr[j], acc[i][j], 0, 0, 0);
    __syncthreads();
  }

#pragma unroll
  for (int i = 0; i < 4; ++i)
#pragma unroll
    for (int j = 0; j < 4; ++j)
#pragma unroll
      for (int r = 0; r < 4; ++r) {
        int row = m0 + wm + i * 16 + quad * 4 + r;
        int col = n0 + wn + j * 16 + l16;
        float v = acc[i][j][r];
        if constexpr (sizeof(OutT) == 2)
          C[(size_t)row * N + col] = (OutT)__float2bfloat16(v);
        else
          C[(size_t)row * N + col] = (OutT)v;
      }
}

// ---------------------------------------------------------------------------
// Split-precision GEMM: C = (Ah+Al)*(Bh+Bl)^T ~ Ah*Bh + Ah*Bl + Al*Bh.
// ---------------------------------------------------------------------------
__global__ __launch_bounds__(256) void gemm_split(
    const bf16_t* __restrict__ Ah, const bf16_t* __restrict__ Al,
    const bf16_t* __restrict__ Bh, const bf16_t* __restrict__ Bl,
    float* __restrict__ C, int M, int N, int K) {
  __shared__ __align__(16) bf16_t Ash[128 * 32];
  __shared__ __align__(16) bf16_t Asl[128 * 32];
  __shared__ __align__(16) bf16_t Bsh[128 * 32];
  __shared__ __align__(16) bf16_t Bsl[128 * 32];
  const int t = threadIdx.x;
  const int wave = t >> 6, lane = t & 63;
  const int quad = lane >> 4, l16 = lane & 15;
  const int m0 = blockIdx.y * 128, n0 = blockIdx.x * 128;
  const int wm = (wave >> 1) * 64, wn = (wave & 1) * 64;

  fragC zero4 = {0.f, 0.f, 0.f, 0.f};
  fragC acc[4][4];
#pragma unroll
  for (int i = 0; i < 4; ++i)
#pragma unroll
    for (int j = 0; j < 4; ++j) acc[i][j] = zero4;

  int rowS[2], colS[2];
#pragma unroll
  for (int i = 0; i < 2; ++i) {
    int e = (wave * 2048 + i * 1024 + lane * 16) >> 1;
    rowS[i] = e >> 5;
    colS[i] = e & 31;
  }

  for (int k0 = 0; k0 < K; k0 += 32) {
#pragma unroll
    for (int i = 0; i < 2; ++i) {
      size_t offA = (size_t)(m0 + rowS[i]) * K + k0 + colS[i];
      size_t offB = (size_t)(n0 + rowS[i]) * K + k0 + colS[i];
      size_t dst = wave * 2048 + i * 1024;
      async_copy16(Ah + offA, (char*)Ash + dst);
      async_copy16(Al + offA, (char*)Asl + dst);
      async_copy16(Bh + offB, (char*)Bsh + dst);
      async_copy16(Bl + offB, (char*)Bsl + dst);
    }
    __syncthreads();
    fragAB ah[4], al[4], bh[4], bl[4];
#pragma unroll
    for (int i = 0; i < 4; ++i) {
      int ro = (wm + i * 16 + l16) * 64 + quad * 16;
      int co = (wn + i * 16 + l16) * 64 + quad * 16;
      ah[i] = *(const fragAB*)((const char*)Ash + ro);
      al[i] = *(const fragAB*)((const char*)Asl + ro);
      bh[i] = *(const fragAB*)((const char*)Bsh + co);
      bl[i] = *(const fragAB*)((const char*)Bsl + co);
    }
#pragma unroll
    for (int i = 0; i < 4; ++i)
#pragma unroll
      for (int j = 0; j < 4; ++j) {
        acc[i][j] = __builtin_amdgcn_mfma_f32_16x16x32_bf16(al[i], bh[j], acc[i][j], 0, 0, 0);
        acc[i][j] = __builtin_amdgcn_mfma_f32_16x16x32_bf16(ah[i], bl[j], acc[i][j], 0, 0, 0);
        acc[i][j] = __builtin_amdgcn_mfma_f32_16x16x32_bf16(ah[i], bh[j], acc[i][j], 0, 0, 0);
      }
    __syncthreads();
  }

#pragma unroll
  for (int i = 0; i < 4; ++i)
#pragma unroll
    for (int j = 0; j < 4; ++j)
#pragma unroll
      for (int r = 0; r < 4; ++r) {
        int row = m0 + wm + i * 16 + quad * 4 + r;
        int col = n0 + wn + j * 16 + l16;
        C[(size_t)row * N + col] = acc[i][j][r];
      }
}

// ---------------------------------------------------------------------------
// RMS-norm (+fp32 weight) + RoPE, fp32 in -> split bf16 hi/lo out.
// proj row stride inStride, head-block starts at inOff. Output stride outStride.
// ---------------------------------------------------------------------------
__global__ __launch_bounds__(256) void rmsnorm_rope_split(
    const float* __restrict__ proj, const float* __restrict__ w,
    const float* __restrict__ cosb, const float* __restrict__ sinb,
    bf16_t* __restrict__ qhi, bf16_t* __restrict__ qlo,
    int inStride, int inOff, int outStride) {
  int s = blockIdx.x, h = blockIdx.y, d = threadIdx.x;
  float x = proj[(size_t)s * inStride + inOff + h * DHEAD + d];
  float ss = x * x;
  ss += __shfl_xor(ss, 1);  ss += __shfl_xor(ss, 2);  ss += __shfl_xor(ss, 4);
  ss += __shfl_xor(ss, 8);  ss += __shfl_xor(ss, 16); ss += __shfl_xor(ss, 32);
  __shared__ float part[4];
  __shared__ float xs[DHEAD];
  if ((threadIdx.x & 63) == 0) part[threadIdx.x >> 6] = ss;
  __syncthreads();
  float tot = part[0] + part[1] + part[2] + part[3];
  float r = rsqrtf(tot * (1.0f / DHEAD) + 1e-6f);
  float xn = x * r * w[d];
  xs[d] = xn;
  __syncthreads();
  float other = xs[(d + 128) & 255];
  float rot = (d < 128) ? -other : other;
  float y = xn * cosb[(size_t)s * DHEAD + d] + rot * sinb[(size_t)s * DHEAD + d];
  bf16_t h2, l2; split2(y, h2, l2);
  size_t oidx = (size_t)s * outStride + h * DHEAD + d;
  qhi[oidx] = h2;
  qlo[oidx] = l2;
}

// ---------------------------------------------------------------------------
// RMS-norm (no weight), fp32 in [S][NKV*D], bf16 out transposed: [NKV][D][S]
// ---------------------------------------------------------------------------
__global__ __launch_bounds__(256) void rmsnorm_vT(
    const float* __restrict__ proj, bf16_t* __restrict__ vt) {
  int s = blockIdx.x, h = blockIdx.y, d = threadIdx.x;
  float x = proj[(size_t)s * NKVH * DHEAD + h * DHEAD + d];
  float ss = x * x;
  ss += __shfl_xor(ss, 1);  ss += __shfl_xor(ss, 2);  ss += __shfl_xor(ss, 4);
  ss += __shfl_xor(ss, 8);  ss += __shfl_xor(ss, 16); ss += __shfl_xor(ss, 32);
  __shared__ float part[4];
  if ((threadIdx.x & 63) == 0) part[threadIdx.x >> 6] = ss;
  __syncthreads();
  float tot = part[0] + part[1] + part[2] + part[3];
  float r = rsqrtf(tot * (1.0f / DHEAD) + 1e-6f);
  vt[((size_t)h * DHEAD + d) * S_LEN + s] = __float2bfloat16(x * r);
}

// ---------------------------------------------------------------------------
// Flash attention, sliding window 512, NO score scale, GQA G=4.
// K/V staged in LDS per 32-key step, XOR source-swizzled (see R6 notes).
// ---------------------------------------------------------------------------
__global__ __launch_bounds__(256) void attn_split(
    const bf16_t* __restrict__ Qhi, const bf16_t* __restrict__ Qlo,
    const bf16_t* __restrict__ Khi, const bf16_t* __restrict__ Klo,
    const bf16_t* __restrict__ Vt, bf16_t* __restrict__ Aout) {
  const int h = blockIdx.y;
  const int qb = blockIdx.x * 64;
  const int wave = threadIdx.x >> 6, lane = threadIdx.x & 63;
  const int quad = lane >> 4, l16 = lane & 15;
  const int qw = qb + wave * 16;
  const int kv = h >> 2;  // G = 4
  const bf16_t* Qh_ = Qhi + h * DHEAD;   // row stride NHQ*DHEAD
  const bf16_t* Ql_ = Qlo + h * DHEAD;
  const bf16_t* Kh_ = Khi + kv * DHEAD;  // row stride NKVH*DHEAD
  const bf16_t* Kl_ = Klo + kv * DHEAD;
  const bf16_t* Vh_ = Vt + (size_t)kv * DHEAD * S_LEN;

  __shared__ __align__(16) bf16_t KshH[32 * 256];
  __shared__ __align__(16) bf16_t KshL[32 * 256];
  __shared__ __align__(16) bf16_t Vsh[256 * 32];
  __shared__ __align__(16) bf16_t Plds[4][16 * 32];

  fragAB qfh[8], qfl[8];
#pragma unroll
  for (int c = 0; c < 8; ++c) {
    size_t off = (size_t)(qw + l16) * (NHQ * DHEAD) + c * 32 + quad * 8;
    qfh[c] = *(const fragAB*)(Qh_ + off);
    qfl[c] = *(const fragAB*)(Ql_ + off);
  }

  int kRow[4], kCol[4], vRow[4], vCol[4];
#pragma unroll
  for (int i = 0; i < 4; ++i) {
    int ci = (i * 4 + wave) * 64 + lane;
    int r = ci >> 5, sc = ci & 31;
    kRow[i] = r;
    kCol[i] = (sc ^ r) * 8;
    int rv = ci >> 2, scv = ci & 3;
    vRow[i] = rv;
    vCol[i] = (scv ^ (rv & 3)) * 8;
  }

  fragC zero4 = {0.f, 0.f, 0.f, 0.f};
  fragC o_acc[16];
#pragma unroll
  for (int c = 0; c < 16; ++c) o_acc[c] = zero4;
  float m_run[4] = {NEG_BIG, NEG_BIG, NEG_BIG, NEG_BIG};
  float l_run[4] = {0.f, 0.f, 0.f, 0.f};
  const float LOG2E = 1.4426950408889634f;

  int k_lo = qb - (WIN - 1);
  if (k_lo < 0) k_lo = 0;
  k_lo &= ~31;

  for (int kb = k_lo; kb < qb + 64; kb += 32) {
#pragma unroll
    for (int i = 0; i < 4; ++i) {
      size_t dst = (size_t)(i * 4 + wave) * 1024;
      size_t koff = (size_t)(kb + kRow[i]) * (NKVH * DHEAD) + kCol[i];
      async_copy16(Kh_ + koff, (char*)KshH + dst);
      async_copy16(Kl_ + koff, (char*)KshL + dst);
      async_copy16(Vh_ + (size_t)vRow[i] * S_LEN + kb + vCol[i], (char*)Vsh + dst);
    }
    __syncthreads();

    fragC s0 = zero4, s1 = zero4;
#pragma unroll
    for (int c = 0; c < 8; ++c) {
      int j = c * 4 + quad;
      int off0 = (l16 * 32 + (j ^ l16)) * 16;
      int off1 = ((16 + l16) * 32 + (j ^ (16 + l16))) * 16;
      fragAB kh0 = *(const fragAB*)((const char*)KshH + off0);
      fragAB kl0 = *(const fragAB*)((const char*)KshL + off0);
      fragAB kh1 = *(const fragAB*)((const char*)KshH + off1);
      fragAB kl1 = *(const fragAB*)((const char*)KshL + off1);
      s0 = __builtin_amdgcn_mfma_f32_16x16x32_bf16(qfl[c], kh0, s0, 0, 0, 0);
      s0 = __builtin_amdgcn_mfma_f32_16x16x32_bf16(qfh[c], kl0, s0, 0, 0, 0);
      s0 = __builtin_amdgcn_mfma_f32_16x16x32_bf16(qfh[c], kh0, s0, 0, 0, 0);
      s1 = __builtin_amdgcn_mfma_f32_16x16x32_bf16(qfl[c], kh1, s1, 0, 0, 0);
      s1 = __builtin_amdgcn_mfma_f32_16x16x32_bf16(qfh[c], kl1, s1, 0, 0, 0);
      s1 = __builtin_amdgcn_mfma_f32_16x16x32_bf16(qfh[c], kh1, s1, 0, 0, 0);
    }

    float p0[4], p1[4], alpha[4];
#pragma unroll
    for (int r = 0; r < 4; ++r) {
      int qi = qw + quad * 4 + r;
      int k0i = kb + l16;
      int k1i = k0i + 16;
      bool v0 = (k0i <= qi) && (qi - k0i < WIN);
      bool v1 = (k1i <= qi) && (qi - k1i < WIN);
      float sv0 = v0 ? s0[r] : NEG_BIG;
      float sv1 = v1 ? s1[r] : NEG_BIG;
      float mx = fmaxf(sv0, sv1);
      mx = fmaxf(mx, __shfl_xor(mx, 1));
      mx = fmaxf(mx, __shfl_xor(mx, 2));
      mx = fmaxf(mx, __shfl_xor(mx, 4));
      mx = fmaxf(mx, __shfl_xor(mx, 8));
      float mn = fmaxf(m_run[r], mx);
      float a  = exp2f(fmaxf(m_run[r] - mn, -80.f) * LOG2E);
      float e0 = v0 ? exp2f(fmaxf(s0[r] - mn, -80.f) * LOG2E) : 0.f;
      float e1 = v1 ? exp2f(fmaxf(s1[r] - mn, -80.f) * LOG2E) : 0.f;
      float rs = e0 + e1;
      rs += __shfl_xor(rs, 1);
      rs += __shfl_xor(rs, 2);
      rs += __shfl_xor(rs, 4);
      rs += __shfl_xor(rs, 8);
      l_run[r] = l_run[r] * a + rs;
      m_run[r] = mn;
      alpha[r] = a; p0[r] = e0; p1[r] = e1;
    }
#pragma unroll
    for (int c = 0; c < 16; ++c)
#pragma unroll
      for (int r = 0; r < 4; ++r) o_acc[c][r] *= alpha[r];

    bf16_t* Pw = Plds[wave];
#pragma unroll
    for (int r = 0; r < 4; ++r) {
      Pw[(quad * 4 + r) * 32 + l16]      = __float2bfloat16(p0[r]);
      Pw[(quad * 4 + r) * 32 + 16 + l16] = __float2bfloat16(p1[r]);
    }
    fragAB pf = *(const fragAB*)((const char*)Pw + l16 * 64 + quad * 16);

#pragma unroll
    for (int c = 0; c < 16; ++c) {
      int d = c * 16 + l16;
      int offv = (d * 4 + (quad ^ (d & 3))) * 16;
      fragAB vf = *(const fragAB*)((const char*)Vsh + offv);
      o_acc[c] = __builtin_amdgcn_mfma_f32_16x16x32_bf16(pf, vf, o_acc[c], 0, 0, 0);
    }
    __syncthreads();
  }

  float inv_l[4];
#pragma unroll
  for (int r = 0; r < 4; ++r) inv_l[r] = 1.0f / l_run[r];
#pragma unroll
  for (int c = 0; c < 16; ++c)
#pragma unroll
    for (int r = 0; r < 4; ++r) {
      int row = qw + quad * 4 + r;
      int col = h * DHEAD + c * 16 + l16;
      Aout[(size_t)row * (NHQ * DHEAD) + col] = __float2bfloat16(o_acc[c][r] * inv_l[r]);
    }
}

// ---------------------------------------------------------------------------
extern "C" void kernel_launch(void* const* d_in, const int* in_sizes, int n_in,
                              void* d_out, int out_size, void* d_ws, size_t ws_size,
                              hipStream_t stream) {
  const float* hid  = (const float*)d_in[0];
  const float* w_q  = (const float*)d_in[1];
  const float* w_k  = (const float*)d_in[2];
  const float* w_v  = (const float*)d_in[3];
  const float* w_o  = (const float*)d_in[4];
  const float* qnw  = (const float*)d_in[5];
  const float* knw  = (const float*)d_in[6];
  const float* cosb = (const float*)d_in[7];
  const float* sinb = (const float*)d_in[8];
  float* outp = (float*)d_out;

  // Workspace (bf16 slots, M1 = 1<<20), peak 46M slots = 92 MiB:
  //  [ 0: 8M)  hidh  -> qh   (after v gemm)
  //  [ 8:16M)  hidl  -> ql
  //  [16:21M)  wTh (2560x2048) -> wvT [16:17M) + vproj f32 [17:21M) after qk gemm
  //  [21:26M)  wTl   -> kh [21:23M), kl [23:25M) after qk gemm  ([25:26M) free)
  //  [26:46M)  projqk f32 (4096x2560) -> aout [26:34M), woT [34:38M), vt [44:46M)
  const size_t M1 = 1048576;
  bf16_t* w = (bf16_t*)d_ws;
  bf16_t* hidh  = w;
  bf16_t* qh    = w;                         // alias hidh
  bf16_t* hidl  = w + 8 * M1;
  bf16_t* ql    = w + 8 * M1;                // alias hidl
  bf16_t* wTh   = w + 16 * M1;
  bf16_t* wvT   = w + 16 * M1;               // alias wTh (after qk gemm)
  float*  vproj = (float*)(w + 17 * M1);     // alias wTh tail
  bf16_t* wTl   = w + 21 * M1;
  bf16_t* kh    = w + 21 * M1;               // alias wTl
  bf16_t* kl    = w + 23 * M1;
  float*  projqk = (float*)(w + 26 * M1);
  bf16_t* aout  = w + 26 * M1;               // alias projqk (after norms)
  bf16_t* woT   = w + 34 * M1;               // alias projqk (after norms)
  bf16_t* vt    = w + 44 * M1;               // alias projqk tail (after norms)

  // phase 0: split hidden; split-transpose [wq|wk] into fused wT
  split_f32<<<(S_LEN * HDIM) / 1024, 256, 0, stream>>>(hid, hidh, hidl, S_LEN * HDIM);
  transpose_split<<<dim3((NHQ * DHEAD) / 32, HDIM / 32), 256, 0, stream>>>(
      w_q, wTh, wTl, HDIM, NHQ * DHEAD);
  transpose_split<<<dim3((NKVH * DHEAD) / 32, HDIM / 32), 256, 0, stream>>>(
      w_k, wTh + (size_t)(NHQ * DHEAD) * HDIM, wTl + (size_t)(NHQ * DHEAD) * HDIM,
      HDIM, NKVH * DHEAD);

  // phase 1: fused q+k split projection (N=2560 -> 640 blocks)
  gemm_split<<<dim3(NQK / 128, S_LEN / 128), 256, 0, stream>>>(
      hidh, hidl, wTh, wTl, projqk, S_LEN, NQK, HDIM);

  // phase 2: v projection (wT dead -> wvT, vproj alias it)
  transpose_cvt<<<dim3((NKVH * DHEAD) / 32, HDIM / 32), 256, 0, stream>>>(w_v, wvT, HDIM, NKVH * DHEAD);
  gemm_bt<float><<<dim3((NKVH * DHEAD) / 128, S_LEN / 128), 256, 0, stream>>>(
      hidh, wvT, vproj, S_LEN, NKVH * DHEAD, HDIM);

  // phase 3: norms (hid dead -> qh/ql; projqk consumed in order q, k, then vt)
  rmsnorm_rope_split<<<dim3(S_LEN, NHQ), 256, 0, stream>>>(
      projqk, qnw, cosb, sinb, qh, ql, NQK, 0, NHQ * DHEAD);
  rmsnorm_rope_split<<<dim3(S_LEN, NKVH), 256, 0, stream>>>(
      projqk, knw, cosb, sinb, kh, kl, NQK, NHQ * DHEAD, NKVH * DHEAD);
  rmsnorm_vT<<<dim3(S_LEN, NKVH), 256, 0, stream>>>(vproj, vt);

  // phase 4: w_o transpose into dead projqk region
  transpose_cvt<<<dim3(HDIM / 32, (NHQ * DHEAD) / 32), 256, 0, stream>>>(w_o, woT, NHQ * DHEAD, HDIM);

  // phase 5: attention -> aout (dead projqk region)
  attn_split<<<dim3(S_LEN / 64, NHQ), 256, 0, stream>>>(qh, ql, kh, kl, vt, aout);

  // phase 6: output projection -> fp32 d_out
  gemm_bt<float><<<dim3(HDIM / 128, S_LEN / 128), 256, 0, stream>>>(aout, woT, outp, S_LEN, HDIM, NHQ * DHEAD);
}

// Round 8
// 521.773 us; speedup vs baseline: 1.3776x; 1.0809x over previous
//
#include <hip/hip_runtime.h>
#include <hip/hip_bf16.h>

#define S_LEN 4096
#define HDIM  2048
#define NHQ   8
#define NKVH  2
#define DHEAD 256
#define WIN   512
#define NQKV  3072   // fused q+k+v projection width (2048 + 512 + 512)

typedef __hip_bfloat16 bf16_t;
using fragAB = __attribute__((ext_vector_type(8))) short;  // 8 bf16
using fragC  = __attribute__((ext_vector_type(4))) float;  // 4 fp32

typedef unsigned int u32;
typedef const __attribute__((address_space(1))) u32* gas_ptr;
typedef __attribute__((address_space(3))) u32* las_ptr;

__device__ __forceinline__ void async_copy16(const void* g, void* l) {
  __builtin_amdgcn_global_load_lds((gas_ptr)g, (las_ptr)l, 16, 0, 0);
}

#define NEG_BIG (-3.0e38f)

__device__ __forceinline__ void split2(float x, bf16_t& hi, bf16_t& lo) {
  bf16_t h = __float2bfloat16(x);
  hi = h;
  lo = __float2bfloat16(x - (float)h);
}

// ---------------------------------------------------------------------------
// Elementwise split fp32 -> bf16 hi + bf16 lo  (n multiple of 1024)
// ---------------------------------------------------------------------------
__global__ __launch_bounds__(256) void split_f32(
    const float* __restrict__ in, bf16_t* __restrict__ hi,
    bf16_t* __restrict__ lo, int n) {
  int i = (blockIdx.x * 256 + threadIdx.x) * 4;
  if (i >= n) return;
  float4 v = *(const float4*)(in + i);
  split2(v.x, hi[i + 0], lo[i + 0]);
  split2(v.y, hi[i + 1], lo[i + 1]);
  split2(v.z, hi[i + 2], lo[i + 2]);
  split2(v.w, hi[i + 3], lo[i + 3]);
}

// ---------------------------------------------------------------------------
// Transpose+convert fp32 [R][C] -> bf16 [C][R]
// ---------------------------------------------------------------------------
__global__ __launch_bounds__(256) void transpose_cvt(
    const float* __restrict__ in, bf16_t* __restrict__ out, int R, int C) {
  __shared__ bf16_t tile[32][33];
  int c0 = blockIdx.x * 32, r0 = blockIdx.y * 32;
  int tx = threadIdx.x & 31, ty = threadIdx.x >> 5;
#pragma unroll
  for (int i = 0; i < 4; ++i)
    tile[ty + i * 8][tx] = __float2bfloat16(in[(size_t)(r0 + ty + i * 8) * C + c0 + tx]);
  __syncthreads();
#pragma unroll
  for (int i = 0; i < 4; ++i)
    out[(size_t)(c0 + ty + i * 8) * R + r0 + tx] = tile[tx][ty + i * 8];
}

// ---------------------------------------------------------------------------
// Transpose+split fp32 [R][C] -> bf16 hi [C][R], bf16 lo [C][R]
// ---------------------------------------------------------------------------
__global__ __launch_bounds__(256) void transpose_split(
    const float* __restrict__ in, bf16_t* __restrict__ hiT,
    bf16_t* __restrict__ loT, int R, int C) {
  __shared__ bf16_t th[32][33];
  __shared__ bf16_t tl[32][33];
  int c0 = blockIdx.x * 32, r0 = blockIdx.y * 32;
  int tx = threadIdx.x & 31, ty = threadIdx.x >> 5;
#pragma unroll
  for (int i = 0; i < 4; ++i) {
    float x = in[(size_t)(r0 + ty + i * 8) * C + c0 + tx];
    bf16_t h, l; split2(x, h, l);
    th[ty + i * 8][tx] = h;
    tl[ty + i * 8][tx] = l;
  }
  __syncthreads();
#pragma unroll
  for (int i = 0; i < 4; ++i) {
    hiT[(size_t)(c0 + ty + i * 8) * R + r0 + tx] = th[tx][ty + i * 8];
    loT[(size_t)(c0 + ty + i * 8) * R + r0 + tx] = tl[tx][ty + i * 8];
  }
}

// ---------------------------------------------------------------------------
// Plain GEMM: C[M][N] = A[M][K]*Bt[N][K]^T; bf16 in, fp32 accum, OutT out.
// ---------------------------------------------------------------------------
template <typename OutT>
__global__ __launch_bounds__(256) void gemm_bt(
    const bf16_t* __restrict__ A, const bf16_t* __restrict__ Bt,
    OutT* __restrict__ C, int M, int N, int K) {
  __shared__ __align__(16) bf16_t As[128 * 32];
  __shared__ __align__(16) bf16_t Bs[128 * 32];
  const int t = threadIdx.x;
  const int wave = t >> 6, lane = t & 63;
  const int quad = lane >> 4, l16 = lane & 15;
  const int m0 = blockIdx.y * 128, n0 = blockIdx.x * 128;
  const int wm = (wave >> 1) * 64, wn = (wave & 1) * 64;

  fragC zero4 = {0.f, 0.f, 0.f, 0.f};
  fragC acc[4][4];
#pragma unroll
  for (int i = 0; i < 4; ++i)
#pragma unroll
    for (int j = 0; j < 4; ++j) acc[i][j] = zero4;

  int rowS[2], colS[2];
#pragma unroll
  for (int i = 0; i < 2; ++i) {
    int e = (wave * 2048 + i * 1024 + lane * 16) >> 1;
    rowS[i] = e >> 5;
    colS[i] = e & 31;
  }

  for (int k0 = 0; k0 < K; k0 += 32) {
#pragma unroll
    for (int i = 0; i < 2; ++i) {
      async_copy16(A + (size_t)(m0 + rowS[i]) * K + k0 + colS[i],
                   (char*)As + wave * 2048 + i * 1024);
      async_copy16(Bt + (size_t)(n0 + rowS[i]) * K + k0 + colS[i],
                   (char*)Bs + wave * 2048 + i * 1024);
    }
    __syncthreads();
    fragAB af[4], bfr[4];
#pragma unroll
    for (int i = 0; i < 4; ++i) {
      af[i]  = *(const fragAB*)((const char*)As + (wm + i * 16 + l16) * 64 + quad * 16);
      bfr[i] = *(const fragAB*)((const char*)Bs + (wn + i * 16 + l16) * 64 + quad * 16);
    }
#pragma unroll
    for (int i = 0; i < 4; ++i)
#pragma unroll
      for (int j = 0; j < 4; ++j)
        acc[i][j] = __builtin_amdgcn_mfma_f32_16x16x32_bf16(af[i], bfr[j], acc[i][j], 0, 0, 0);
    __syncthreads();
  }

#pragma unroll
  for (int i = 0; i < 4; ++i)
#pragma unroll
    for (int j = 0; j < 4; ++j)
#pragma unroll
      for (int r = 0; r < 4; ++r) {
        int row = m0 + wm + i * 16 + quad * 4 + r;
        int col = n0 + wn + j * 16 + l16;
        float v = acc[i][j][r];
        if constexpr (sizeof(OutT) == 2)
          C[(size_t)row * N + col] = (OutT)__float2bfloat16(v);
        else
          C[(size_t)row * N + col] = (OutT)v;
      }
}

// ---------------------------------------------------------------------------
// Split-precision GEMM: C = (Ah+Al)*(Bh+Bl)^T ~ Ah*Bh + Ah*Bl + Al*Bh.
// ---------------------------------------------------------------------------
__global__ __launch_bounds__(256) void gemm_split(
    const bf16_t* __restrict__ Ah, const bf16_t* __restrict__ Al,
    const bf16_t* __restrict__ Bh, const bf16_t* __restrict__ Bl,
    float* __restrict__ C, int M, int N, int K) {
  __shared__ __align__(16) bf16_t Ash[128 * 32];
  __shared__ __align__(16) bf16_t Asl[128 * 32];
  __shared__ __align__(16) bf16_t Bsh[128 * 32];
  __shared__ __align__(16) bf16_t Bsl[128 * 32];
  const int t = threadIdx.x;
  const int wave = t >> 6, lane = t & 63;
  const int quad = lane >> 4, l16 = lane & 15;
  const int m0 = blockIdx.y * 128, n0 = blockIdx.x * 128;
  const int wm = (wave >> 1) * 64, wn = (wave & 1) * 64;

  fragC zero4 = {0.f, 0.f, 0.f, 0.f};
  fragC acc[4][4];
#pragma unroll
  for (int i = 0; i < 4; ++i)
#pragma unroll
    for (int j = 0; j < 4; ++j) acc[i][j] = zero4;

  int rowS[2], colS[2];
#pragma unroll
  for (int i = 0; i < 2; ++i) {
    int e = (wave * 2048 + i * 1024 + lane * 16) >> 1;
    rowS[i] = e >> 5;
    colS[i] = e & 31;
  }

  for (int k0 = 0; k0 < K; k0 += 32) {
#pragma unroll
    for (int i = 0; i < 2; ++i) {
      size_t offA = (size_t)(m0 + rowS[i]) * K + k0 + colS[i];
      size_t offB = (size_t)(n0 + rowS[i]) * K + k0 + colS[i];
      size_t dst = wave * 2048 + i * 1024;
      async_copy16(Ah + offA, (char*)Ash + dst);
      async_copy16(Al + offA, (char*)Asl + dst);
      async_copy16(Bh + offB, (char*)Bsh + dst);
      async_copy16(Bl + offB, (char*)Bsl + dst);
    }
    __syncthreads();
    fragAB ah[4], al[4], bh[4], bl[4];
#pragma unroll
    for (int i = 0; i < 4; ++i) {
      int ro = (wm + i * 16 + l16) * 64 + quad * 16;
      int co = (wn + i * 16 + l16) * 64 + quad * 16;
      ah[i] = *(const fragAB*)((const char*)Ash + ro);
      al[i] = *(const fragAB*)((const char*)Asl + ro);
      bh[i] = *(const fragAB*)((const char*)Bsh + co);
      bl[i] = *(const fragAB*)((const char*)Bsl + co);
    }
#pragma unroll
    for (int i = 0; i < 4; ++i)
#pragma unroll
      for (int j = 0; j < 4; ++j) {
        acc[i][j] = __builtin_amdgcn_mfma_f32_16x16x32_bf16(al[i], bh[j], acc[i][j], 0, 0, 0);
        acc[i][j] = __builtin_amdgcn_mfma_f32_16x16x32_bf16(ah[i], bl[j], acc[i][j], 0, 0, 0);
        acc[i][j] = __builtin_amdgcn_mfma_f32_16x16x32_bf16(ah[i], bh[j], acc[i][j], 0, 0, 0);
      }
    __syncthreads();
  }

#pragma unroll
  for (int i = 0; i < 4; ++i)
#pragma unroll
    for (int j = 0; j < 4; ++j)
#pragma unroll
      for (int r = 0; r < 4; ++r) {
        int row = m0 + wm + i * 16 + quad * 4 + r;
        int col = n0 + wn + j * 16 + l16;
        C[(size_t)row * N + col] = acc[i][j][r];
      }
}

// ---------------------------------------------------------------------------
// RMS-norm (+fp32 weight) + RoPE, fp32 in -> split bf16 hi/lo out.
// proj row stride inStride, head-block starts at inOff. Output stride outStride.
// ---------------------------------------------------------------------------
__global__ __launch_bounds__(256) void rmsnorm_rope_split(
    const float* __restrict__ proj, const float* __restrict__ w,
    const float* __restrict__ cosb, const float* __restrict__ sinb,
    bf16_t* __restrict__ qhi, bf16_t* __restrict__ qlo,
    int inStride, int inOff, int outStride) {
  int s = blockIdx.x, h = blockIdx.y, d = threadIdx.x;
  float x = proj[(size_t)s * inStride + inOff + h * DHEAD + d];
  float ss = x * x;
  ss += __shfl_xor(ss, 1);  ss += __shfl_xor(ss, 2);  ss += __shfl_xor(ss, 4);
  ss += __shfl_xor(ss, 8);  ss += __shfl_xor(ss, 16); ss += __shfl_xor(ss, 32);
  __shared__ float part[4];
  __shared__ float xs[DHEAD];
  if ((threadIdx.x & 63) == 0) part[threadIdx.x >> 6] = ss;
  __syncthreads();
  float tot = part[0] + part[1] + part[2] + part[3];
  float r = rsqrtf(tot * (1.0f / DHEAD) + 1e-6f);
  float xn = x * r * w[d];
  xs[d] = xn;
  __syncthreads();
  float other = xs[(d + 128) & 255];
  float rot = (d < 128) ? -other : other;
  float y = xn * cosb[(size_t)s * DHEAD + d] + rot * sinb[(size_t)s * DHEAD + d];
  bf16_t h2, l2; split2(y, h2, l2);
  size_t oidx = (size_t)s * outStride + h * DHEAD + d;
  qhi[oidx] = h2;
  qlo[oidx] = l2;
}

// ---------------------------------------------------------------------------
// RMS-norm (no weight), fp32 in (stride/offset), bf16 out transposed [NKV][D][S]
// ---------------------------------------------------------------------------
__global__ __launch_bounds__(256) void rmsnorm_vT(
    const float* __restrict__ proj, bf16_t* __restrict__ vt,
    int inStride, int inOff) {
  int s = blockIdx.x, h = blockIdx.y, d = threadIdx.x;
  float x = proj[(size_t)s * inStride + inOff + h * DHEAD + d];
  float ss = x * x;
  ss += __shfl_xor(ss, 1);  ss += __shfl_xor(ss, 2);  ss += __shfl_xor(ss, 4);
  ss += __shfl_xor(ss, 8);  ss += __shfl_xor(ss, 16); ss += __shfl_xor(ss, 32);
  __shared__ float part[4];
  if ((threadIdx.x & 63) == 0) part[threadIdx.x >> 6] = ss;
  __syncthreads();
  float tot = part[0] + part[1] + part[2] + part[3];
  float r = rsqrtf(tot * (1.0f / DHEAD) + 1e-6f);
  vt[((size_t)h * DHEAD + d) * S_LEN + s] = __float2bfloat16(x * r);
}

// ---------------------------------------------------------------------------
// Flash attention, sliding window 512, NO score scale, GQA G=4.
// K/V staged in LDS per 32-key step, XOR source-swizzled (see R6 notes).
// ---------------------------------------------------------------------------
__global__ __launch_bounds__(256) void attn_split(
    const bf16_t* __restrict__ Qhi, const bf16_t* __restrict__ Qlo,
    const bf16_t* __restrict__ Khi, const bf16_t* __restrict__ Klo,
    const bf16_t* __restrict__ Vt, bf16_t* __restrict__ Aout) {
  const int h = blockIdx.y;
  const int qb = blockIdx.x * 64;
  const int wave = threadIdx.x >> 6, lane = threadIdx.x & 63;
  const int quad = lane >> 4, l16 = lane & 15;
  const int qw = qb + wave * 16;
  const int kv = h >> 2;  // G = 4
  const bf16_t* Qh_ = Qhi + h * DHEAD;   // row stride NHQ*DHEAD
  const bf16_t* Ql_ = Qlo + h * DHEAD;
  const bf16_t* Kh_ = Khi + kv * DHEAD;  // row stride NKVH*DHEAD
  const bf16_t* Kl_ = Klo + kv * DHEAD;
  const bf16_t* Vh_ = Vt + (size_t)kv * DHEAD * S_LEN;

  __shared__ __align__(16) bf16_t KshH[32 * 256];
  __shared__ __align__(16) bf16_t KshL[32 * 256];
  __shared__ __align__(16) bf16_t Vsh[256 * 32];
  __shared__ __align__(16) bf16_t Plds[4][16 * 32];

  fragAB qfh[8], qfl[8];
#pragma unroll
  for (int c = 0; c < 8; ++c) {
    size_t off = (size_t)(qw + l16) * (NHQ * DHEAD) + c * 32 + quad * 8;
    qfh[c] = *(const fragAB*)(Qh_ + off);
    qfl[c] = *(const fragAB*)(Ql_ + off);
  }

  int kRow[4], kCol[4], vRow[4], vCol[4];
#pragma unroll
  for (int i = 0; i < 4; ++i) {
    int ci = (i * 4 + wave) * 64 + lane;
    int r = ci >> 5, sc = ci & 31;
    kRow[i] = r;
    kCol[i] = (sc ^ r) * 8;
    int rv = ci >> 2, scv = ci & 3;
    vRow[i] = rv;
    vCol[i] = (scv ^ (rv & 3)) * 8;
  }

  fragC zero4 = {0.f, 0.f, 0.f, 0.f};
  fragC o_acc[16];
#pragma unroll
  for (int c = 0; c < 16; ++c) o_acc[c] = zero4;
  float m_run[4] = {NEG_BIG, NEG_BIG, NEG_BIG, NEG_BIG};
  float l_run[4] = {0.f, 0.f, 0.f, 0.f};
  const float LOG2E = 1.4426950408889634f;

  int k_lo = qb - (WIN - 1);
  if (k_lo < 0) k_lo = 0;
  k_lo &= ~31;

  for (int kb = k_lo; kb < qb + 64; kb += 32) {
#pragma unroll
    for (int i = 0; i < 4; ++i) {
      size_t dst = (size_t)(i * 4 + wave) * 1024;
      size_t koff = (size_t)(kb + kRow[i]) * (NKVH * DHEAD) + kCol[i];
      async_copy16(Kh_ + koff, (char*)KshH + dst);
      async_copy16(Kl_ + koff, (char*)KshL + dst);
      async_copy16(Vh_ + (size_t)vRow[i] * S_LEN + kb + vCol[i], (char*)Vsh + dst);
    }
    __syncthreads();

    fragC s0 = zero4, s1 = zero4;
#pragma unroll
    for (int c = 0; c < 8; ++c) {
      int j = c * 4 + quad;
      int off0 = (l16 * 32 + (j ^ l16)) * 16;
      int off1 = ((16 + l16) * 32 + (j ^ (16 + l16))) * 16;
      fragAB kh0 = *(const fragAB*)((const char*)KshH + off0);
      fragAB kl0 = *(const fragAB*)((const char*)KshL + off0);
      fragAB kh1 = *(const fragAB*)((const char*)KshH + off1);
      fragAB kl1 = *(const fragAB*)((const char*)KshL + off1);
      s0 = __builtin_amdgcn_mfma_f32_16x16x32_bf16(qfl[c], kh0, s0, 0, 0, 0);
      s0 = __builtin_amdgcn_mfma_f32_16x16x32_bf16(qfh[c], kl0, s0, 0, 0, 0);
      s0 = __builtin_amdgcn_mfma_f32_16x16x32_bf16(qfh[c], kh0, s0, 0, 0, 0);
      s1 = __builtin_amdgcn_mfma_f32_16x16x32_bf16(qfl[c], kh1, s1, 0, 0, 0);
      s1 = __builtin_amdgcn_mfma_f32_16x16x32_bf16(qfh[c], kl1, s1, 0, 0, 0);
      s1 = __builtin_amdgcn_mfma_f32_16x16x32_bf16(qfh[c], kh1, s1, 0, 0, 0);
    }

    float p0[4], p1[4], alpha[4];
#pragma unroll
    for (int r = 0; r < 4; ++r) {
      int qi = qw + quad * 4 + r;
      int k0i = kb + l16;
      int k1i = k0i + 16;
      bool v0 = (k0i <= qi) && (qi - k0i < WIN);
      bool v1 = (k1i <= qi) && (qi - k1i < WIN);
      float sv0 = v0 ? s0[r] : NEG_BIG;
      float sv1 = v1 ? s1[r] : NEG_BIG;
      float mx = fmaxf(sv0, sv1);
      mx = fmaxf(mx, __shfl_xor(mx, 1));
      mx = fmaxf(mx, __shfl_xor(mx, 2));
      mx = fmaxf(mx, __shfl_xor(mx, 4));
      mx = fmaxf(mx, __shfl_xor(mx, 8));
      float mn = fmaxf(m_run[r], mx);
      float a  = exp2f(fmaxf(m_run[r] - mn, -80.f) * LOG2E);
      float e0 = v0 ? exp2f(fmaxf(s0[r] - mn, -80.f) * LOG2E) : 0.f;
      float e1 = v1 ? exp2f(fmaxf(s1[r] - mn, -80.f) * LOG2E) : 0.f;
      float rs = e0 + e1;
      rs += __shfl_xor(rs, 1);
      rs += __shfl_xor(rs, 2);
      rs += __shfl_xor(rs, 4);
      rs += __shfl_xor(rs, 8);
      l_run[r] = l_run[r] * a + rs;
      m_run[r] = mn;
      alpha[r] = a; p0[r] = e0; p1[r] = e1;
    }
#pragma unroll
    for (int c = 0; c < 16; ++c)
#pragma unroll
      for (int r = 0; r < 4; ++r) o_acc[c][r] *= alpha[r];

    bf16_t* Pw = Plds[wave];
#pragma unroll
    for (int r = 0; r < 4; ++r) {
      Pw[(quad * 4 + r) * 32 + l16]      = __float2bfloat16(p0[r]);
      Pw[(quad * 4 + r) * 32 + 16 + l16] = __float2bfloat16(p1[r]);
    }
    fragAB pf = *(const fragAB*)((const char*)Pw + l16 * 64 + quad * 16);

#pragma unroll
    for (int c = 0; c < 16; ++c) {
      int d = c * 16 + l16;
      int offv = (d * 4 + (quad ^ (d & 3))) * 16;
      fragAB vf = *(const fragAB*)((const char*)Vsh + offv);
      o_acc[c] = __builtin_amdgcn_mfma_f32_16x16x32_bf16(pf, vf, o_acc[c], 0, 0, 0);
    }
    __syncthreads();
  }

  float inv_l[4];
#pragma unroll
  for (int r = 0; r < 4; ++r) inv_l[r] = 1.0f / l_run[r];
#pragma unroll
  for (int c = 0; c < 16; ++c)
#pragma unroll
    for (int r = 0; r < 4; ++r) {
      int row = qw + quad * 4 + r;
      int col = h * DHEAD + c * 16 + l16;
      Aout[(size_t)row * (NHQ * DHEAD) + col] = __float2bfloat16(o_acc[c][r] * inv_l[r]);
    }
}

// ---------------------------------------------------------------------------
extern "C" void kernel_launch(void* const* d_in, const int* in_sizes, int n_in,
                              void* d_out, int out_size, void* d_ws, size_t ws_size,
                              hipStream_t stream) {
  const float* hid  = (const float*)d_in[0];
  const float* w_q  = (const float*)d_in[1];
  const float* w_k  = (const float*)d_in[2];
  const float* w_v  = (const float*)d_in[3];
  const float* w_o  = (const float*)d_in[4];
  const float* qnw  = (const float*)d_in[5];
  const float* knw  = (const float*)d_in[6];
  const float* cosb = (const float*)d_in[7];
  const float* sinb = (const float*)d_in[8];
  float* outp = (float*)d_out;

  // Workspace (bf16 slots, M1 = 1<<20), peak 52M slots = 104 MiB:
  //  [ 0: 8M)  hidh  -> qh  (after qkv gemm)
  //  [ 8:16M)  hidl  -> ql
  //  [16:22M)  wTh (3072x2048) -> kh[16:18M), kl[18:20M), vt[20:22M) after gemm
  //  [22:28M)  wTl   -> woT[22:26M) after gemm
  //  [28:52M)  projqkv f32 (4096x3072) -> aout[28:36M) after norms
  const size_t M1 = 1048576;
  bf16_t* w = (bf16_t*)d_ws;
  bf16_t* hidh  = w;
  bf16_t* qh    = w;                         // alias hidh
  bf16_t* hidl  = w + 8 * M1;
  bf16_t* ql    = w + 8 * M1;                // alias hidl
  bf16_t* wTh   = w + 16 * M1;
  bf16_t* kh    = w + 16 * M1;               // alias wTh
  bf16_t* kl    = w + 18 * M1;
  bf16_t* vt    = w + 20 * M1;
  bf16_t* wTl   = w + 22 * M1;
  bf16_t* woT   = w + 22 * M1;               // alias wTl
  float*  projqkv = (float*)(w + 28 * M1);
  bf16_t* aout  = w + 28 * M1;               // alias projqkv (after norms)

  // phase 0: split hidden; split-transpose [wq|wk|wv] into fused wT [3072][2048]
  split_f32<<<(S_LEN * HDIM) / 1024, 256, 0, stream>>>(hid, hidh, hidl, S_LEN * HDIM);
  transpose_split<<<dim3((NHQ * DHEAD) / 32, HDIM / 32), 256, 0, stream>>>(
      w_q, wTh, wTl, HDIM, NHQ * DHEAD);
  transpose_split<<<dim3((NKVH * DHEAD) / 32, HDIM / 32), 256, 0, stream>>>(
      w_k, wTh + (size_t)(NHQ * DHEAD) * HDIM, wTl + (size_t)(NHQ * DHEAD) * HDIM,
      HDIM, NKVH * DHEAD);
  transpose_split<<<dim3((NKVH * DHEAD) / 32, HDIM / 32), 256, 0, stream>>>(
      w_v, wTh + (size_t)(NHQ * DHEAD + NKVH * DHEAD) * HDIM,
      wTl + (size_t)(NHQ * DHEAD + NKVH * DHEAD) * HDIM, HDIM, NKVH * DHEAD);

  // phase 1: fused q+k+v split projection (N=3072 -> 768 blocks = 3.0/CU uniform)
  gemm_split<<<dim3(NQKV / 128, S_LEN / 128), 256, 0, stream>>>(
      hidh, hidl, wTh, wTl, projqkv, S_LEN, NQKV, HDIM);

  // phase 2: norms (hid/wT dead -> qh/ql/kh/kl/vt targets)
  rmsnorm_rope_split<<<dim3(S_LEN, NHQ), 256, 0, stream>>>(
      projqkv, qnw, cosb, sinb, qh, ql, NQKV, 0, NHQ * DHEAD);
  rmsnorm_rope_split<<<dim3(S_LEN, NKVH), 256, 0, stream>>>(
      projqkv, knw, cosb, sinb, kh, kl, NQKV, NHQ * DHEAD, NKVH * DHEAD);
  rmsnorm_vT<<<dim3(S_LEN, NKVH), 256, 0, stream>>>(
      projqkv, vt, NQKV, NHQ * DHEAD + NKVH * DHEAD);

  // phase 3: w_o transpose into dead wTl region
  transpose_cvt<<<dim3(HDIM / 32, (NHQ * DHEAD) / 32), 256, 0, stream>>>(w_o, woT, NHQ * DHEAD, HDIM);

  // phase 4: attention -> aout (dead projqkv region)
  attn_split<<<dim3(S_LEN / 64, NHQ), 256, 0, stream>>>(qh, ql, kh, kl, vt, aout);

  // phase 5: output projection -> fp32 d_out (512 blocks = 2.0/CU uniform)
  gemm_bt<float><<<dim3(HDIM / 128, S_LEN / 128), 256, 0, stream>>>(aout, woT, outp, S_LEN, HDIM, NHQ * DHEAD);
}